// Round 2
// baseline (549.053 us; speedup 1.0000x reference)
//
#include <hip/hip_runtime.h>
#include <hip/hip_bf16.h>
#include <cstdint>
#include <cstddef>

// MoE expert FFN: h = gelu(x @ w1[e]^T + b1[e]); out = h @ w2[e]^T + b2[e]
// R2: counted-vmcnt 4-slot ring pipeline (T3+T4), 256-wide tiles, 8 waves,
// LDS read-balance swizzle (T2, both-sides involution), XCD swizzle (T1),
// setprio (T5). One barrier per K-tile: s_waitcnt vmcnt(8) lgkmcnt(0); s_barrier.

typedef __bf16 bf16x8 __attribute__((ext_vector_type(8)));
typedef float f32x4 __attribute__((ext_vector_type(4)));
typedef unsigned short u16x8 __attribute__((ext_vector_type(8)));

#define BK 32

__device__ __forceinline__ unsigned short f2bf(float f) {
  unsigned u = __builtin_bit_cast(unsigned, f);
  u += 0x7FFFu + ((u >> 16) & 1u);   // RNE
  return (unsigned short)(u >> 16);
}

__device__ __forceinline__ void gload16(const void* g, void* lds) {
  __builtin_amdgcn_global_load_lds(
      (const __attribute__((address_space(1))) void*)g,
      (__attribute__((address_space(3))) void*)lds, 16, 0, 0);
}

// ---------------- setup: tile tables (BM=256 for GEMM1, BM=128 for GEMM2) ----
__global__ void build_tiles2(const int* __restrict__ cnt, int E,
                             int4* __restrict__ t1, int* __restrict__ n1,
                             int4* __restrict__ t2, int* __restrict__ n2) {
  if (threadIdx.x == 0 && blockIdx.x == 0) {
    int nt = 0, start = 0;
    for (int e = 0; e < E; ++e) {
      int c = cnt[e];
      for (int t = 0; t < c; t += 256) {
        int4 v; v.x = e; v.y = start + t; v.z = (c - t < 256 ? c - t : 256); v.w = 0;
        t1[nt++] = v;
      }
      start += c;
    }
    *n1 = nt;
    nt = 0; start = 0;
    for (int e = 0; e < E; ++e) {
      int c = cnt[e];
      for (int t = 0; t < c; t += 128) {
        int4 v; v.x = e; v.y = start + t; v.z = (c - t < 128 ? c - t : 128); v.w = 0;
        t2[nt++] = v;
      }
      start += c;
    }
    *n2 = nt;
  }
}

// ---------------- f32 -> bf16 convert (vectorized) ---------------------------
__global__ void cvt_kernel(const float* __restrict__ src,
                           unsigned short* __restrict__ dst, long n) {
  long i = ((long)blockIdx.x * blockDim.x + threadIdx.x) * 8;
  const long stride = (long)gridDim.x * blockDim.x * 8;
  for (; i < n; i += stride) {
    float4 a = *reinterpret_cast<const float4*>(src + i);
    float4 b = *reinterpret_cast<const float4*>(src + i + 4);
    u16x8 o;
    o[0] = f2bf(a.x); o[1] = f2bf(a.y); o[2] = f2bf(a.z); o[3] = f2bf(a.w);
    o[4] = f2bf(b.x); o[5] = f2bf(b.y); o[6] = f2bf(b.z); o[7] = f2bf(b.w);
    *reinterpret_cast<u16x8*>(dst + i) = o;
  }
}

// ---------------- grouped GEMM, counted-vmcnt ring pipeline ------------------
// C[t,n] = A[t,:] . W[e][n,:] (+bias, opt gelu). A:[T,K] bf16, W:[E,N,K] bf16.
// BMT x 256 tile, BK=32, 8 waves (2M x 4N), per-wave (BMT/2) x 64 output.
// LDS: 4-slot ring, slot = K-tile%4. Swizzle: col16 ^= (row>>1)&3 (involution,
// applied on the pre-swizzled global source AND the ds_read address).
template <int BMT, int GELU, int OUTBF>
__global__ __launch_bounds__(512, 2) void grouped_gemm(
    const unsigned short* __restrict__ A, const unsigned short* __restrict__ W,
    const float* __restrict__ bias, void* __restrict__ Cv,
    const int4* __restrict__ tbl, const int* __restrict__ ntp,
    const int N, const int K) {
  constexpr int BN = 256;
  constexpr int MREP = BMT / 32;

  // T1: bijective XCD swizzle on the flat block id (m204 form).
  const int gx = gridDim.x;
  const int nwg = gx * gridDim.y;
  const int flat = blockIdx.y * gx + blockIdx.x;
  const int q = nwg >> 3, r = nwg & 7, xc = flat & 7, dd = flat >> 3;
  const int orig = (xc < r ? xc * (q + 1) : r * (q + 1) + (xc - r) * q) + dd;
  const int mt = orig / gx;
  const int bx = orig - mt * gx;

  if (mt >= *ntp) return;
  const int4 ti = tbl[mt];
  const int e = ti.x, row0 = ti.y, rows = ti.z;
  const int bcol = bx * BN;

  __shared__ alignas(16) unsigned short sA[4][BMT * BK];
  __shared__ alignas(16) unsigned short sB[4][BN * BK];

  const int tid = threadIdx.x;
  const int lane = tid & 63;
  const int wave = tid >> 6;
  const int wr = wave >> 2;   // 0..1
  const int wc = wave & 3;    // 0..3
  const int lr = lane & 15;
  const int lhi = lane >> 4;  // 0..3

  const unsigned short* __restrict__ Aseg = A + (size_t)row0 * K;
  const unsigned short* __restrict__ Wexp = W + ((size_t)e * N + bcol) * K;

  // Staging: dest-linear (gload_lds writes base + lane*16), source pre-swizzled.
  // One gload16 per wave covers 16 rows of 64B: row = i*128 + wave*16 + (lane>>2),
  // dest col16 = lane&3; LDS offset = 16*lane from wave base (verified identity).
  const int srow_w = wave * 16 + (lane >> 2);  // + i*128
  const int sc16 = lane & 3;

  const int nk = K / BK;

  auto stage = [&](int kt, int slot) {
#pragma unroll
    for (int i = 0; i < BMT / 128; ++i) {
      const int row = i * 128 + srow_w;
      const int rc = row < rows ? row : rows - 1;           // clamp inside segment
      const int c16 = sc16 ^ ((row >> 1) & 3);              // inverse swizzle (involution)
      gload16(Aseg + (size_t)rc * K + kt * BK + c16 * 8,
              (char*)&sA[slot][0] + i * 8192 + wave * 1024);
    }
#pragma unroll
    for (int i = 0; i < 2; ++i) {
      const int row = i * 128 + srow_w;
      const int c16 = sc16 ^ ((row >> 1) & 3);
      gload16(Wexp + (size_t)row * K + kt * BK + c16 * 8,
              (char*)&sB[slot][0] + i * 8192 + wave * 1024);
    }
  };

  f32x4 acc[MREP][4] = {};

  // Prologue: stage tiles 0,1,2 (slots 0,1,2). K is 1024/4096 here, so nk >= 3.
  stage(0, 0);
  stage(1, 1);
  stage(2 < nk ? 2 : nk - 1, 2);

  for (int t = 0; t < nk; ++t) {
    // Counted wait: outstanding = tiles t+1, t+2 (8 loads for BMT=256, 6 for 128)
    // -> completes exactly tile t. lgkmcnt(0) guarantees all prior ds_reads are
    // serviced before any wave can overwrite a slot (race-free ring reuse).
    if constexpr (BMT == 256)
      asm volatile("s_waitcnt vmcnt(8) lgkmcnt(0)\n\ts_barrier" ::: "memory");
    else
      asm volatile("s_waitcnt vmcnt(6) lgkmcnt(0)\n\ts_barrier" ::: "memory");

    // Issue prefetch for tile t+3 into slot (t+3)&3 (= slot of tile t-1, whose
    // reads were drained at this barrier). Clamped dup-stages keep vmcnt uniform.
    {
      const int kt = (t + 3 < nk) ? t + 3 : nk - 1;
      stage(kt, (t + 3) & 3);
    }

    const int slot = t & 3;
    bf16x8 aF[MREP], bF[4];
#pragma unroll
    for (int m = 0; m < MREP; ++m) {
      const int row = wr * (BMT / 2) + m * 16 + lr;
      const int c = lhi ^ ((row >> 1) & 3);                 // swizzled read
      aF[m] = *reinterpret_cast<const bf16x8*>(&sA[slot][row * BK + c * 8]);
    }
#pragma unroll
    for (int n = 0; n < 4; ++n) {
      const int row = wc * 64 + n * 16 + lr;
      const int c = lhi ^ ((row >> 1) & 3);
      bF[n] = *reinterpret_cast<const bf16x8*>(&sB[slot][row * BK + c * 8]);
    }
    __builtin_amdgcn_s_setprio(1);
#pragma unroll
    for (int m = 0; m < MREP; ++m)
#pragma unroll
      for (int n = 0; n < 4; ++n)
        acc[m][n] = __builtin_amdgcn_mfma_f32_16x16x32_bf16(aF[m], bF[n], acc[m][n], 0, 0, 0);
    __builtin_amdgcn_s_setprio(0);
  }

  // Epilogue. C/D layout (m89-verified): col = lane&15, row = (lane>>4)*4 + reg.
  const float* __restrict__ be = bias + (size_t)e * N;
  const int colL = wc * 64 + lr;          // + n*16, local to tile
  const int rowB = wr * (BMT / 2) + (lhi << 2);
#pragma unroll
  for (int n = 0; n < 4; ++n) {
    const int col = bcol + colL + n * 16;
    const float bv = be[col];
#pragma unroll
    for (int m = 0; m < MREP; ++m) {
#pragma unroll
      for (int j = 0; j < 4; ++j) {
        const int rr = rowB + m * 16 + j;
        if (rr < rows) {
          float v = acc[m][n][j] + bv;
          if (GELU) v = 0.5f * v * (1.0f + erff(v * 0.7071067811865476f));
          const size_t idx = (size_t)(row0 + rr) * N + col;
          if (OUTBF) ((unsigned short*)Cv)[idx] = f2bf(v);
          else       ((float*)Cv)[idx] = v;
        }
      }
    }
  }
}

extern "C" void kernel_launch(void* const* d_in, const int* in_sizes, int n_in,
                              void* d_out, int out_size, void* d_ws, size_t ws_size,
                              hipStream_t stream) {
  const float* inp = (const float*)d_in[0];
  const float* w1  = (const float*)d_in[1];
  const float* b1  = (const float*)d_in[2];
  const float* w2  = (const float*)d_in[3];
  const float* b2  = (const float*)d_in[4];
  const int*   cnt = (const int*)d_in[5];

  const int E = in_sizes[5];
  const int H = in_sizes[2] / E;       // b1 is [E,H]
  const int D = in_sizes[4] / E;       // b2 is [E,D]
  const int T = in_sizes[0] / D;       // inp is [T,D]

  char* ws = (char*)d_ws;
  int4* tbl1 = (int4*)ws;                       // <= 64 entries
  int4* tbl2 = (int4*)(ws + 1024);              // <= 128 entries
  int* n1 = (int*)(ws + 3072);
  int* n2 = (int*)(ws + 3076);
  size_t off = 4096;
  unsigned short* inp_bf = (unsigned short*)(ws + off); off += (size_t)T * D * 2;
  unsigned short* w1_bf  = (unsigned short*)(ws + off); off += (size_t)E * H * D * 2;
  unsigned short* w2_bf  = (unsigned short*)(ws + off); off += (size_t)E * D * H * 2;
  unsigned short* h_bf   = (unsigned short*)(ws + off); off += (size_t)T * H * 2;
  (void)ws_size; (void)n_in; (void)out_size;

  build_tiles2<<<1, 64, 0, stream>>>(cnt, E, tbl1, n1, tbl2, n2);

  cvt_kernel<<<2048, 256, 0, stream>>>(inp, inp_bf, (long)T * D);
  cvt_kernel<<<2048, 256, 0, stream>>>(w1, w1_bf, (long)E * H * D);
  cvt_kernel<<<2048, 256, 0, stream>>>(w2, w2_bf, (long)E * D * H);

  // GEMM1: [T,D] x [E,H,D] -> h [T,H], gelu, bf16 out.  256x256 tiles.
  dim3 g1(H / 256, T / 256 + E);
  grouped_gemm<256, 1, 1><<<g1, 512, 0, stream>>>(inp_bf, w1_bf, b1, h_bf, tbl1, n1, H, D);
  // GEMM2: [T,H] x [E,D,H] -> out [T,D], f32 out.  128x256 tiles (256 live blocks).
  dim3 g2(D / 256, T / 128 + E);
  grouped_gemm<128, 0, 0><<<g2, 512, 0, stream>>>(h_bf, w2_bf, b2, d_out, tbl2, n2, D, H);
}

// Round 3
// 496.195 us; speedup vs baseline: 1.1065x; 1.1065x over previous
//
#include <hip/hip_runtime.h>
#include <hip/hip_bf16.h>
#include <cstdint>
#include <cstddef>

// MoE expert FFN: h = gelu(x @ w1[e]^T + b1[e]); out = h @ w2[e]^T + b2[e]
// R3: 256x256 tile, BK=32, 4-slot LDS ring, per-phase interleave (m201-style):
// per K-tile 4 phases {ds-load quadrant frags | stage 1/4 next+3 tile | barrier |
// setprio1 | 8 MFMA | setprio0 | barrier}; counted vmcnt(8/4/0) ONLY at tile
// boundaries, placed BEFORE the barrier. LDS read-balance XOR swizzle (proven
// 0-conflict in R2). GEMM2 uses split-K=2 + combine pass (grid 128 -> 320 blocks).

typedef __bf16 bf16x8 __attribute__((ext_vector_type(8)));
typedef float f32x4 __attribute__((ext_vector_type(4)));
typedef unsigned short u16x8 __attribute__((ext_vector_type(8)));

#define BK 32

__device__ __forceinline__ unsigned short f2bf(float f) {
  unsigned u = __builtin_bit_cast(unsigned, f);
  u += 0x7FFFu + ((u >> 16) & 1u);   // RNE
  return (unsigned short)(u >> 16);
}

__device__ __forceinline__ void gload16(const void* g, void* lds) {
  __builtin_amdgcn_global_load_lds(
      (const __attribute__((address_space(1))) void*)g,
      (__attribute__((address_space(3))) void*)lds, 16, 0, 0);
}

// ---------------- setup: tile table (BM=256, shared by both GEMMs) ----------
__global__ void build_tiles(const int* __restrict__ cnt, int E,
                            int4* __restrict__ tbl, int* __restrict__ ntp) {
  if (threadIdx.x == 0 && blockIdx.x == 0) {
    int nt = 0, start = 0;
    for (int e = 0; e < E; ++e) {
      int c = cnt[e];
      for (int t = 0; t < c; t += 256) {
        int4 v; v.x = e; v.y = start + t; v.z = (c - t < 256 ? c - t : 256); v.w = 0;
        tbl[nt++] = v;
      }
      start += c;
    }
    *ntp = nt;
  }
}

// ---------------- f32 -> bf16 convert (vectorized) ---------------------------
__global__ void cvt_kernel(const float* __restrict__ src,
                           unsigned short* __restrict__ dst, long n) {
  long i = ((long)blockIdx.x * blockDim.x + threadIdx.x) * 8;
  const long stride = (long)gridDim.x * blockDim.x * 8;
  for (; i < n; i += stride) {
    float4 a = *reinterpret_cast<const float4*>(src + i);
    float4 b = *reinterpret_cast<const float4*>(src + i + 4);
    u16x8 o;
    o[0] = f2bf(a.x); o[1] = f2bf(a.y); o[2] = f2bf(a.z); o[3] = f2bf(a.w);
    o[4] = f2bf(b.x); o[5] = f2bf(b.y); o[6] = f2bf(b.z); o[7] = f2bf(b.w);
    *reinterpret_cast<u16x8*>(dst + i) = o;
  }
}

// ---------------- split-K combine: out = p0 + p1 (bias already in p0) --------
__global__ void combine_kernel(const float* __restrict__ p0,
                               const float* __restrict__ p1,
                               float* __restrict__ out, long n) {
  long i = ((long)blockIdx.x * blockDim.x + threadIdx.x) * 4;
  const long stride = (long)gridDim.x * blockDim.x * 4;
  for (; i < n; i += stride) {
    float4 a = *reinterpret_cast<const float4*>(p0 + i);
    float4 b = *reinterpret_cast<const float4*>(p1 + i);
    float4 o; o.x = a.x + b.x; o.y = a.y + b.y; o.z = a.z + b.z; o.w = a.w + b.w;
    *reinterpret_cast<float4*>(out + i) = o;
  }
}

#define PHASE_MFMA(AF, BF, I0, J0)                                              \
  __builtin_amdgcn_s_setprio(1);                                                \
  _Pragma("unroll")                                                             \
  for (int m = 0; m < 4; ++m) {                                                 \
    _Pragma("unroll")                                                           \
    for (int n = 0; n < 2; ++n)                                                 \
      acc[(I0) + m][(J0) + n] = __builtin_amdgcn_mfma_f32_16x16x32_bf16(        \
          AF[m], BF[n], acc[(I0) + m][(J0) + n], 0, 0, 0);                      \
  }                                                                             \
  __builtin_amdgcn_s_setprio(0);

// ---------------- grouped GEMM, ring + per-phase interleave ------------------
// C[t,n] = A[t, ks*K/SPLITK : ...] . W[e][n, same] (+bias on ks==0, opt gelu).
// 512 thr / 8 waves (2Mx4N), per-wave C = 128x64 = 8x4 frags of 16x16.
template <int GELU, int OUTBF, int SPLITK>
__global__ __launch_bounds__(512, 2) void grouped_gemm(
    const unsigned short* __restrict__ A, const unsigned short* __restrict__ W,
    const float* __restrict__ bias, void* __restrict__ Cv,
    const int4* __restrict__ tbl, const int* __restrict__ ntp,
    const int N, const int K, const int Ttot) {
  const int ks = (SPLITK > 1) ? blockIdx.z : 0;
  const int Kloc = K / SPLITK;

  // T1: bijective XCD swizzle on flat (x,y) id.
  const int gx = gridDim.x;
  const int nwg = gx * gridDim.y;
  const int flat = blockIdx.y * gx + blockIdx.x;
  const int q = nwg >> 3, r = nwg & 7, xc = flat & 7, dd = flat >> 3;
  const int orig = (xc < r ? xc * (q + 1) : r * (q + 1) + (xc - r) * q) + dd;
  const int mt = orig / gx;
  const int bx = orig - mt * gx;

  if (mt >= *ntp) return;
  const int4 ti = tbl[mt];
  const int e = ti.x, row0 = ti.y, rows = ti.z;
  const int bcol = bx * 256;

  __shared__ alignas(16) unsigned short sA[4][256 * BK];
  __shared__ alignas(16) unsigned short sB[4][256 * BK];

  const int tid = threadIdx.x;
  const int lane = tid & 63;
  const int wave = tid >> 6;
  const int wr = wave >> 2;   // 0..1  (row half: 128 rows)
  const int wc = wave & 3;    // 0..3  (64-col stripe)
  const int lr = lane & 15;
  const int lhi = lane >> 4;  // 0..3
  const int chsw = (lr >> 1) & 3;        // read-side XOR term (base rows %16==0)

  const unsigned short* __restrict__ Aseg = A + (size_t)row0 * K + (size_t)ks * Kloc;
  const unsigned short* __restrict__ Wexp =
      W + ((size_t)e * N + bcol) * K + (size_t)ks * Kloc;

  // Staging geometry: unit u in 0..3 = {A rows 0-127, A rows 128-255, B 0-127,
  // B 128-255}; thread -> row = (u&1)*128 + (tid>>2), chunk = tid&3 (16B).
  // Dest linear (wave-uniform base + lane*16); source chunk pre-swizzled.
  const int srow = tid >> 2;
  const int sc = tid & 3;

  auto stage = [&](int kt, int slot, int u) {
    const int row = (u & 1) * 128 + srow;
    const int cg = sc ^ ((row >> 1) & 3);   // involution (verified 0-conflict, R2)
    if (u < 2) {
      const int rc = row < rows ? row : rows - 1;
      gload16(Aseg + (size_t)rc * K + kt * BK + cg * 8,
              (char*)&sA[slot][0] + (u & 1) * 8192 + wave * 1024);
    } else {
      gload16(Wexp + (size_t)row * K + kt * BK + cg * 8,
              (char*)&sB[slot][0] + (u & 1) * 8192 + wave * 1024);
    }
  };

  f32x4 acc[8][4] = {};
  bf16x8 a0[4], a1[4], b0[2], b1[2];

  auto ldA = [&](int slot, int rh, bf16x8* dst) {
#pragma unroll
    for (int m = 0; m < 4; ++m) {
      const int rrow = wr * 128 + rh * 64 + m * 16 + lr;
      dst[m] = *reinterpret_cast<const bf16x8*>(
          &sA[slot][rrow * BK + (lhi ^ chsw) * 8]);
    }
  };
  auto ldB = [&](int slot, int chh, bf16x8* dst) {
#pragma unroll
    for (int n = 0; n < 2; ++n) {
      const int rrow = wc * 64 + chh * 32 + n * 16 + lr;
      dst[n] = *reinterpret_cast<const bf16x8*>(
          &sB[slot][rrow * BK + (lhi ^ chsw) * 8]);
    }
  };

  const int nk = Kloc / BK;   // >= 32 here

  // Prologue: stage tiles 0,1,2 into slots 0,1,2 (12 loads/thread, FIFO order).
  for (int t = 0; t < 3; ++t) {
#pragma unroll
    for (int u = 0; u < 4; ++u) stage(t, t, u);
  }
  asm volatile("s_waitcnt vmcnt(8)" ::: "memory");   // tile 0 landed
  __builtin_amdgcn_s_barrier();

  for (int t = 0; t < nk; ++t) {
    const int slot = t & 3;
    const int pf = t + 3;
    const int pfs = pf & 3;
    const bool dopf = pf < nk;   // uniform

    // phase 0: A(rh0) + B(ch0) frags; stage unit 0; MFMA quadrant (0,0)
    ldA(slot, 0, a0);
    ldB(slot, 0, b0);
    if (dopf) stage(pf, pfs, 0);
    __builtin_amdgcn_s_barrier();
    PHASE_MFMA(a0, b0, 0, 0);
    __builtin_amdgcn_s_barrier();

    // phase 1: A(rh1); stage unit 1; MFMA (1,0)
    ldA(slot, 1, a1);
    if (dopf) stage(pf, pfs, 1);
    __builtin_amdgcn_s_barrier();
    PHASE_MFMA(a1, b0, 4, 0);
    __builtin_amdgcn_s_barrier();

    // phase 2: B(ch1); stage unit 2; MFMA (0,1) reusing a0
    ldB(slot, 1, b1);
    if (dopf) stage(pf, pfs, 2);
    __builtin_amdgcn_s_barrier();
    PHASE_MFMA(a0, b1, 0, 2);
    __builtin_amdgcn_s_barrier();

    // phase 3: stage unit 3; MFMA (1,1)
    if (dopf) stage(pf, pfs, 3);
    __builtin_amdgcn_s_barrier();
    PHASE_MFMA(a1, b1, 4, 2);

    // Tile boundary: drain tile t+1's stages BEFORE the barrier so all waves'
    // staged data is visible after it. In-flight = tiles t+1..min(t+3,nk-1).
    if (t + 3 < nk)      asm volatile("s_waitcnt vmcnt(8)" ::: "memory");
    else if (t + 2 < nk) asm volatile("s_waitcnt vmcnt(4)" ::: "memory");
    else if (t + 1 < nk) asm volatile("s_waitcnt vmcnt(0)" ::: "memory");
    __builtin_amdgcn_s_barrier();
  }

  // Epilogue. Frag C/D layout (m89): col = lane&15, row = (lane>>4)*4 + reg.
  const float* __restrict__ be = bias + (size_t)e * N;
  float* __restrict__ outF = (float*)Cv + (size_t)ks * Ttot * N;
#pragma unroll
  for (int jf = 0; jf < 4; ++jf) {
    const int col = bcol + wc * 64 + (jf >> 1) * 32 + (jf & 1) * 16 + lr;
    const float bv = (SPLITK == 1 || ks == 0) ? be[col] : 0.0f;
#pragma unroll
    for (int i = 0; i < 8; ++i) {
      const int rbase = wr * 128 + (i >> 2) * 64 + (i & 3) * 16 + (lhi << 2);
#pragma unroll
      for (int j = 0; j < 4; ++j) {
        const int rr = rbase + j;
        if (rr < rows) {
          float v = acc[i][jf][j] + bv;
          if (GELU) v = 0.5f * v * (1.0f + erff(v * 0.7071067811865476f));
          const size_t idx = (size_t)(row0 + rr) * N + col;
          if (OUTBF) ((unsigned short*)Cv)[idx] = f2bf(v);
          else       outF[idx] = v;
        }
      }
    }
  }
}

extern "C" void kernel_launch(void* const* d_in, const int* in_sizes, int n_in,
                              void* d_out, int out_size, void* d_ws, size_t ws_size,
                              hipStream_t stream) {
  const float* inp = (const float*)d_in[0];
  const float* w1  = (const float*)d_in[1];
  const float* b1  = (const float*)d_in[2];
  const float* w2  = (const float*)d_in[3];
  const float* b2  = (const float*)d_in[4];
  const int*   cnt = (const int*)d_in[5];

  const int E = in_sizes[5];
  const int H = in_sizes[2] / E;       // b1 is [E,H]
  const int D = in_sizes[4] / E;       // b2 is [E,D]
  const int T = in_sizes[0] / D;       // inp is [T,D]

  char* ws = (char*)d_ws;
  int4* tbl = (int4*)ws;               // <= 72 entries
  int* ntp = (int*)(ws + 2048);
  size_t off = 4096;
  unsigned short* inp_bf = (unsigned short*)(ws + off); off += (size_t)T * D * 2;
  unsigned short* w1_bf  = (unsigned short*)(ws + off); off += (size_t)E * H * D * 2;
  unsigned short* w2_bf  = (unsigned short*)(ws + off); off += (size_t)E * D * H * 2;
  unsigned short* h_bf   = (unsigned short*)(ws + off); off += (size_t)T * H * 2;
  // psum (2 x T*D f32 = 64 MB) overlays w1_bf (64 MB, dead after GEMM1).
  float* psum = (float*)w1_bf;
  (void)ws_size; (void)n_in; (void)out_size;

  build_tiles<<<1, 64, 0, stream>>>(cnt, E, tbl, ntp);

  cvt_kernel<<<2048, 256, 0, stream>>>(inp, inp_bf, (long)T * D);
  cvt_kernel<<<2048, 256, 0, stream>>>(w1, w1_bf, (long)E * H * D);
  cvt_kernel<<<2048, 256, 0, stream>>>(w2, w2_bf, (long)E * D * H);

  // GEMM1: [T,D] x [E,H,D] -> h [T,H], +b1, gelu, bf16 out.
  dim3 g1(H / 256, T / 256 + E, 1);
  grouped_gemm<1, 1, 1><<<g1, 512, 0, stream>>>(inp_bf, w1_bf, b1, h_bf,
                                                tbl, ntp, H, D, T);
  // GEMM2: [T,H] x [E,D,H] -> psum[2][T,D] (bias in ks=0), split-K=2.
  dim3 g2(D / 256, T / 256 + E, 2);
  grouped_gemm<0, 0, 2><<<g2, 512, 0, stream>>>(h_bf, w2_bf, b2, psum,
                                                tbl, ntp, D, H, T);
  // out = psum0 + psum1
  combine_kernel<<<2048, 256, 0, stream>>>(psum, psum + (size_t)T * D,
                                           (float*)d_out, (long)T * D);
}

// Round 4
// 396.432 us; speedup vs baseline: 1.3850x; 1.2517x over previous
//
#include <hip/hip_runtime.h>
#include <hip/hip_bf16.h>
#include <cstdint>
#include <cstddef>

// MoE expert FFN: h = gelu(x @ w1[e]^T + b1[e]); out = h @ w2[e]^T + b2[e]
// R4: revert to R1's proven 128x128/4-wave/BK=32/2-phase dbuf structure
// (3+ blocks/CU — cross-block overlap covers the per-iter vmcnt drain, which
// R2/R3's 1-block/CU 8-wave structures could not). Add only proven levers:
//   (1) T2 LDS swizzle (chunk ^= (row>>1)&3, linear dest + pre-swizzled source
//       + same involution on read) — R2-verified 0 bank conflicts.
//   (2) T1 bijective XCD chunking (m204) for L2 locality.
//   (3) split-K=2 on GEMM2 (occupancy 19%->~38%) + f32 combine pass.

typedef __bf16 bf16x8 __attribute__((ext_vector_type(8)));
typedef float f32x4 __attribute__((ext_vector_type(4)));
typedef unsigned short u16x8 __attribute__((ext_vector_type(8)));

#define BM 128
#define BN 128
#define BK 32

__device__ __forceinline__ unsigned short f2bf(float f) {
  unsigned u = __builtin_bit_cast(unsigned, f);
  u += 0x7FFFu + ((u >> 16) & 1u);   // RNE
  return (unsigned short)(u >> 16);
}

__device__ __forceinline__ void gload16(const void* g, void* lds) {
  __builtin_amdgcn_global_load_lds(
      (const __attribute__((address_space(1))) void*)g,
      (__attribute__((address_space(3))) void*)lds, 16, 0, 0);
}

// ---------------- setup: tile table (BM=128, shared) -------------------------
__global__ void build_tiles(const int* __restrict__ cnt, int E,
                            int4* __restrict__ tbl, int* __restrict__ ntp) {
  if (threadIdx.x == 0 && blockIdx.x == 0) {
    int nt = 0, start = 0;
    for (int e = 0; e < E; ++e) {
      int c = cnt[e];
      for (int t = 0; t < c; t += BM) {
        int4 v; v.x = e; v.y = start + t; v.z = (c - t < BM ? c - t : BM); v.w = 0;
        tbl[nt++] = v;
      }
      start += c;
    }
    *ntp = nt;
  }
}

// ---------------- f32 -> bf16 convert (vectorized) ---------------------------
__global__ void cvt_kernel(const float* __restrict__ src,
                           unsigned short* __restrict__ dst, long n) {
  long i = ((long)blockIdx.x * blockDim.x + threadIdx.x) * 8;
  const long stride = (long)gridDim.x * blockDim.x * 8;
  for (; i < n; i += stride) {
    float4 a = *reinterpret_cast<const float4*>(src + i);
    float4 b = *reinterpret_cast<const float4*>(src + i + 4);
    u16x8 o;
    o[0] = f2bf(a.x); o[1] = f2bf(a.y); o[2] = f2bf(a.z); o[3] = f2bf(a.w);
    o[4] = f2bf(b.x); o[5] = f2bf(b.y); o[6] = f2bf(b.z); o[7] = f2bf(b.w);
    *reinterpret_cast<u16x8*>(dst + i) = o;
  }
}

// ---------------- split-K combine: out = p0 + p1 (bias already in p0) --------
__global__ void combine_kernel(const float* __restrict__ p0,
                               const float* __restrict__ p1,
                               float* __restrict__ out, long n) {
  long i = ((long)blockIdx.x * blockDim.x + threadIdx.x) * 4;
  const long stride = (long)gridDim.x * blockDim.x * 4;
  for (; i < n; i += stride) {
    float4 a = *reinterpret_cast<const float4*>(p0 + i);
    float4 b = *reinterpret_cast<const float4*>(p1 + i);
    float4 o; o.x = a.x + b.x; o.y = a.y + b.y; o.z = a.z + b.z; o.w = a.w + b.w;
    *reinterpret_cast<float4*>(out + i) = o;
  }
}

// ---------------- grouped GEMM (R1 structure + swizzles) ---------------------
// C[t,n] = A[t, ks*Kloc:(ks+1)*Kloc] . W[e][n, same] (+bias at ks==0, opt gelu)
// A: [T,K] bf16, W: [E,N,K] bf16. 256 thr / 4 waves (2x2), 64x64 C per wave.
template <int GELU, int OUTBF, int SPLITK>
__global__ __launch_bounds__(256, 2) void grouped_gemm(
    const unsigned short* __restrict__ A, const unsigned short* __restrict__ W,
    const float* __restrict__ bias, void* __restrict__ Cv,
    const int4* __restrict__ tbl, const int* __restrict__ ntp,
    const int N, const int K, const int Ttot) {
  const int ks = (SPLITK > 1) ? blockIdx.z : 0;
  const int Kloc = K / SPLITK;

  // T1: bijective XCD chunking (m204). Each XCD gets a contiguous run of the
  // natural x-major order (n-sweep within m-tile, then next m-tile).
  const int gx = gridDim.x;
  const int nwg = gx * gridDim.y;
  const int flat = blockIdx.y * gx + blockIdx.x;
  const int q = nwg >> 3, r = nwg & 7, xc = flat & 7, dd = flat >> 3;
  const int orig = (xc < r ? xc * (q + 1) : r * (q + 1) + (xc - r) * q) + dd;
  const int mt = orig / gx;
  const int bx = orig - mt * gx;

  if (mt >= *ntp) return;
  const int4 ti = tbl[mt];
  const int e = ti.x, row0 = ti.y, rows = ti.z;
  const int bcol = bx * BN;

  __shared__ alignas(16) unsigned short sA[2][BM * BK];
  __shared__ alignas(16) unsigned short sB[2][BN * BK];

  const int tid = threadIdx.x;
  const int lane = tid & 63;
  const int wave = tid >> 6;
  const int wr = wave >> 1;  // 0..1
  const int wc = wave & 1;   // 0..1
  const int lr = lane & 15;
  const int lhi = lane >> 4; // 0..3

  const unsigned short* __restrict__ Aseg = A + (size_t)ks * Kloc;
  const unsigned short* __restrict__ Wexp = W + (size_t)e * N * K + (size_t)ks * Kloc;

  // Staging: dest row = wave*16 + (lane>>2) (+i*64), dest chunk = lane&3.
  // LDS byte (row,chunk) = row*64 + chunk*16 == wave*1024 + lane*16 (linear,
  // as gload_lds requires). Source chunk = dest chunk ^ ((dest_row>>1)&3);
  // the XOR term is thread-constant (rows differ by 64 -> same term).
  const int srow = wave * 16 + (lane >> 2);   // + i*64
  const int cg = (lane & 3) ^ ((srow >> 1) & 3);
  const int a0 = srow < rows ? srow : rows - 1;        // clamp inside segment
  const int a1 = srow + 64 < rows ? srow + 64 : rows - 1;
  const unsigned short* gA0 = Aseg + (size_t)(row0 + a0) * K + cg * 8;
  const unsigned short* gA1 = Aseg + (size_t)(row0 + a1) * K + cg * 8;
  const unsigned short* gB0 = Wexp + (size_t)(bcol + srow) * K + cg * 8;
  const unsigned short* gB1 = Wexp + (size_t)(bcol + srow + 64) * K + cg * 8;

  f32x4 acc[4][4] = {};
  const int aRowB = wr * 64 + lr;
  const int bRowB = wc * 64 + lr;
  // Swizzled read chunk: want global chunk lhi of row (16a + lr) ->
  // stored at chunk lhi ^ ((lr>>1)&3).  (R2-verified: 0 bank conflicts.)
  const int rsw = (lhi ^ ((lr >> 1) & 3)) * 8;

  const int nk = Kloc / BK;
  {
    char* da = (char*)&sA[0][0] + wave * 1024;
    char* db = (char*)&sB[0][0] + wave * 1024;
    gload16(gA0, da);
    gload16(gA1, da + 4096);
    gload16(gB0, db);
    gload16(gB1, db + 4096);
  }
  __syncthreads();

  int buf = 0;
  for (int t = 0; t < nk; ++t) {
    if (t + 1 < nk) {
      const int k0 = (t + 1) * BK;
      char* da = (char*)&sA[buf ^ 1][0] + wave * 1024;
      char* db = (char*)&sB[buf ^ 1][0] + wave * 1024;
      gload16(gA0 + k0, da);
      gload16(gA1 + k0, da + 4096);
      gload16(gB0 + k0, db);
      gload16(gB1 + k0, db + 4096);
    }
    bf16x8 af[4], bfr[4];
#pragma unroll
    for (int m = 0; m < 4; ++m)
      af[m] = *reinterpret_cast<const bf16x8*>(&sA[buf][(aRowB + m * 16) * BK + rsw]);
#pragma unroll
    for (int n = 0; n < 4; ++n)
      bfr[n] = *reinterpret_cast<const bf16x8*>(&sB[buf][(bRowB + n * 16) * BK + rsw]);
#pragma unroll
    for (int m = 0; m < 4; ++m)
#pragma unroll
      for (int n = 0; n < 4; ++n)
        acc[m][n] = __builtin_amdgcn_mfma_f32_16x16x32_bf16(af[m], bfr[n], acc[m][n], 0, 0, 0);
    __syncthreads();  // drains prefetch + barrier; covered by 3+ blocks/CU
    buf ^= 1;
  }

  // Epilogue. C/D layout (m89): col = lane&15, row = (lane>>4)*4 + reg.
  const float* __restrict__ be = bias + (size_t)e * N;
  float* __restrict__ outF = (float*)Cv + (size_t)ks * Ttot * N;
  const int colBase = bcol + wc * 64 + lr;
  const int rowBase = wr * 64 + (lhi << 2);
#pragma unroll
  for (int n = 0; n < 4; ++n) {
    const int col = colBase + n * 16;
    const float bv = (SPLITK == 1 || ks == 0) ? be[col] : 0.0f;
#pragma unroll
    for (int m = 0; m < 4; ++m) {
      const int r0 = rowBase + m * 16;
#pragma unroll
      for (int j = 0; j < 4; ++j) {
        const int rr = r0 + j;
        if (rr < rows) {
          float v = acc[m][n][j] + bv;
          if (GELU) v = 0.5f * v * (1.0f + erff(v * 0.7071067811865476f));
          const size_t idx = (size_t)(row0 + rr) * N + col;
          if (OUTBF) ((unsigned short*)Cv)[idx] = f2bf(v);
          else       outF[idx] = v;
        }
      }
    }
  }
}

extern "C" void kernel_launch(void* const* d_in, const int* in_sizes, int n_in,
                              void* d_out, int out_size, void* d_ws, size_t ws_size,
                              hipStream_t stream) {
  const float* inp = (const float*)d_in[0];
  const float* w1  = (const float*)d_in[1];
  const float* b1  = (const float*)d_in[2];
  const float* w2  = (const float*)d_in[3];
  const float* b2  = (const float*)d_in[4];
  const int*   cnt = (const int*)d_in[5];

  const int E = in_sizes[5];
  const int H = in_sizes[2] / E;       // b1 is [E,H]
  const int D = in_sizes[4] / E;       // b2 is [E,D]
  const int T = in_sizes[0] / D;       // inp is [T,D]

  char* ws = (char*)d_ws;
  int4* tbl = (int4*)ws;               // <= 72 entries
  int* ntp = (int*)(ws + 2048);
  size_t off = 4096;
  unsigned short* inp_bf = (unsigned short*)(ws + off); off += (size_t)T * D * 2;
  unsigned short* w1_bf  = (unsigned short*)(ws + off); off += (size_t)E * H * D * 2;
  unsigned short* w2_bf  = (unsigned short*)(ws + off); off += (size_t)E * D * H * 2;
  unsigned short* h_bf   = (unsigned short*)(ws + off); off += (size_t)T * H * 2;
  // psum (2 x T*D f32 = 64 MB) overlays w1_bf (64 MB, dead after GEMM1).
  float* psum = (float*)w1_bf;
  (void)ws_size; (void)n_in; (void)out_size;

  build_tiles<<<1, 64, 0, stream>>>(cnt, E, tbl, ntp);

  cvt_kernel<<<2048, 256, 0, stream>>>(inp, inp_bf, (long)T * D);
  cvt_kernel<<<2048, 256, 0, stream>>>(w1, w1_bf, (long)E * H * D);
  cvt_kernel<<<2048, 256, 0, stream>>>(w2, w2_bf, (long)E * D * H);

  const int maxTiles = T / BM + E;
  // GEMM1: [T,D] x [E,H,D] -> h [T,H], +b1, gelu, bf16 out.
  dim3 g1(H / BN, maxTiles, 1);
  grouped_gemm<1, 1, 1><<<g1, 256, 0, stream>>>(inp_bf, w1_bf, b1, h_bf,
                                                tbl, ntp, H, D, T);
  // GEMM2: [T,H] x [E,D,H] -> psum[2][T,D] (bias in ks=0), split-K=2.
  dim3 g2(D / BN, maxTiles, 2);
  grouped_gemm<0, 0, 2><<<g2, 256, 0, stream>>>(h_bf, w2_bf, b2, psum,
                                                tbl, ntp, D, H, T);
  // out = psum0 + psum1
  combine_kernel<<<2048, 256, 0, stream>>>(psum, psum + (size_t)T * D,
                                           (float*)d_out, (long)T * D);
}

// Round 5
// 389.455 us; speedup vs baseline: 1.4098x; 1.0179x over previous
//
#include <hip/hip_runtime.h>
#include <hip/hip_bf16.h>
#include <cstdint>
#include <cstddef>

// MoE expert FFN: h = gelu(x @ w1[e]^T + b1[e]); out = h @ w2[e]^T + b2[e]
// R5: R1's proven 128x128 / 4-wave / BK=32 structure, plus:
//   (1) T2 LDS swizzle (R2-verified: 0 bank conflicts), baked into pointers.
//   (2) NO XCD remap (R4 isolated it as a regression: 146->172us, FETCH +45%).
//   (3) split-K=2 on GEMM2 (576 -> 1152 blocks).
//   (4) NEW: 3-slot LDS ring (48KB, still 3 blocks/CU) with counted vmcnt:
//       per iter {s_waitcnt vmcnt(4); s_barrier; ds_read frags; stage t+2;
//       16 MFMA} — tile t+1's loads stay in flight across the barrier, so
//       L2/L3 latency (~200-900cy) has ~2 iterations to hide instead of being
//       drained serially every step (R1-R4's vmcnt(0) syncthreads).

typedef __bf16 bf16x8 __attribute__((ext_vector_type(8)));
typedef float f32x4 __attribute__((ext_vector_type(4)));
typedef unsigned short u16x8 __attribute__((ext_vector_type(8)));

#define BM 128
#define BN 128
#define BK 32

__device__ __forceinline__ unsigned short f2bf(float f) {
  unsigned u = __builtin_bit_cast(unsigned, f);
  u += 0x7FFFu + ((u >> 16) & 1u);   // RNE
  return (unsigned short)(u >> 16);
}

__device__ __forceinline__ void gload16(const void* g, void* lds) {
  __builtin_amdgcn_global_load_lds(
      (const __attribute__((address_space(1))) void*)g,
      (__attribute__((address_space(3))) void*)lds, 16, 0, 0);
}

// ---------------- setup: tile table (BM=128, shared) -------------------------
__global__ void build_tiles(const int* __restrict__ cnt, int E,
                            int4* __restrict__ tbl, int* __restrict__ ntp) {
  if (threadIdx.x == 0 && blockIdx.x == 0) {
    int nt = 0, start = 0;
    for (int e = 0; e < E; ++e) {
      int c = cnt[e];
      for (int t = 0; t < c; t += BM) {
        int4 v; v.x = e; v.y = start + t; v.z = (c - t < BM ? c - t : BM); v.w = 0;
        tbl[nt++] = v;
      }
      start += c;
    }
    *ntp = nt;
  }
}

// ---------------- f32 -> bf16 convert (vectorized) ---------------------------
__global__ void cvt_kernel(const float* __restrict__ src,
                           unsigned short* __restrict__ dst, long n) {
  long i = ((long)blockIdx.x * blockDim.x + threadIdx.x) * 8;
  const long stride = (long)gridDim.x * blockDim.x * 8;
  for (; i < n; i += stride) {
    float4 a = *reinterpret_cast<const float4*>(src + i);
    float4 b = *reinterpret_cast<const float4*>(src + i + 4);
    u16x8 o;
    o[0] = f2bf(a.x); o[1] = f2bf(a.y); o[2] = f2bf(a.z); o[3] = f2bf(a.w);
    o[4] = f2bf(b.x); o[5] = f2bf(b.y); o[6] = f2bf(b.z); o[7] = f2bf(b.w);
    *reinterpret_cast<u16x8*>(dst + i) = o;
  }
}

// ---------------- split-K combine: out = p0 + p1 (bias already in p0) --------
__global__ void combine_kernel(const float* __restrict__ p0,
                               const float* __restrict__ p1,
                               float* __restrict__ out, long n) {
  long i = ((long)blockIdx.x * blockDim.x + threadIdx.x) * 4;
  const long stride = (long)gridDim.x * blockDim.x * 4;
  for (; i < n; i += stride) {
    float4 a = *reinterpret_cast<const float4*>(p0 + i);
    float4 b = *reinterpret_cast<const float4*>(p1 + i);
    float4 o; o.x = a.x + b.x; o.y = a.y + b.y; o.z = a.z + b.z; o.w = a.w + b.w;
    *reinterpret_cast<float4*>(out + i) = o;
  }
}

// ---------------- grouped GEMM (128x128, 4 waves, 3-slot ring) ---------------
// C[t,n] = A[t, ks*Kloc:(ks+1)*Kloc] . W[e][n, same] (+bias at ks==0, opt gelu)
template <int GELU, int OUTBF, int SPLITK>
__global__ __launch_bounds__(256, 2) void grouped_gemm(
    const unsigned short* __restrict__ A, const unsigned short* __restrict__ W,
    const float* __restrict__ bias, void* __restrict__ Cv,
    const int4* __restrict__ tbl, const int* __restrict__ ntp,
    const int N, const int K, const int Ttot) {
  const int ks = (SPLITK > 1) ? blockIdx.z : 0;
  const int Kloc = K / SPLITK;

  const int mt = blockIdx.y;           // natural order (R4: XCD remap regressed)
  const int bx = blockIdx.x;
  if (mt >= *ntp) return;
  const int4 ti = tbl[mt];
  const int e = ti.x, row0 = ti.y, rows = ti.z;
  const int bcol = bx * BN;

  __shared__ alignas(16) unsigned short sA[3][BM * BK];   // 3 x 8KB
  __shared__ alignas(16) unsigned short sB[3][BN * BK];   // 3 x 8KB  (48KB tot)

  const int tid = threadIdx.x;
  const int lane = tid & 63;
  const int wave = tid >> 6;
  const int wr = wave >> 1;  // 0..1
  const int wc = wave & 1;   // 0..1
  const int lr = lane & 15;
  const int lhi = lane >> 4; // 0..3

  const unsigned short* __restrict__ Aseg = A + (size_t)ks * Kloc;
  const unsigned short* __restrict__ Wexp = W + (size_t)e * N * K + (size_t)ks * Kloc;

  // Staging: dest row = wave*16 + (lane>>2) (+i*64), dest chunk = lane&3;
  // LDS byte = row*64 + chunk*16 == wave*1024 + lane*16 (linear, as gload_lds
  // requires). Source chunk = dest ^ ((row>>1)&3) — thread-constant, baked in.
  const int srow = wave * 16 + (lane >> 2);   // + i*64
  const int cg = (lane & 3) ^ ((srow >> 1) & 3);
  const int a0 = srow < rows ? srow : rows - 1;
  const int a1 = srow + 64 < rows ? srow + 64 : rows - 1;
  const unsigned short* gA0 = Aseg + (size_t)(row0 + a0) * K + cg * 8;
  const unsigned short* gA1 = Aseg + (size_t)(row0 + a1) * K + cg * 8;
  const unsigned short* gB0 = Wexp + (size_t)(bcol + srow) * K + cg * 8;
  const unsigned short* gB1 = Wexp + (size_t)(bcol + srow + 64) * K + cg * 8;

  auto stage = [&](int kt, int slot) {
    const int k0 = kt * BK;
    char* da = (char*)&sA[slot][0] + wave * 1024;
    char* db = (char*)&sB[slot][0] + wave * 1024;
    gload16(gA0 + k0, da);
    gload16(gA1 + k0, da + 4096);
    gload16(gB0 + k0, db);
    gload16(gB1 + k0, db + 4096);
  };

  f32x4 acc[4][4] = {};
  const int aRowB = wr * 64 + lr;
  const int bRowB = wc * 64 + lr;
  // Read-side swizzle (row-term is lr-only: other row components are %16==0).
  const int rsw = (lhi ^ ((lr >> 1) & 3)) * 8;

  const int nk = Kloc / BK;   // >= 16 here

  // Prologue: 2 tiles in flight (8 loads/thread).
  stage(0, 0);
  stage(1, 1);

  for (int t = 0; t < nk; ++t) {
    // Wait ONLY tile t (own-wave drain), keep tile t+1's 4 loads in flight;
    // barrier makes all waves' tile-t data visible. Writes to slot (t+2)%3
    // (= slot (t-1)%3) are safe after this barrier: every wave's slot-(t-1)
    // ds_reads were lgkm-retired before its MFMAs, hence before it got here.
    if (t + 1 < nk) asm volatile("s_waitcnt vmcnt(4)" ::: "memory");
    else            asm volatile("s_waitcnt vmcnt(0)" ::: "memory");
    __builtin_amdgcn_s_barrier();

    const int slot = t % 3;
    bf16x8 af[4], bfr[4];
#pragma unroll
    for (int m = 0; m < 4; ++m)
      af[m] = *reinterpret_cast<const bf16x8*>(&sA[slot][(aRowB + m * 16) * BK + rsw]);
#pragma unroll
    for (int n = 0; n < 4; ++n)
      bfr[n] = *reinterpret_cast<const bf16x8*>(&sB[slot][(bRowB + n * 16) * BK + rsw]);

    if (t + 2 < nk) stage(t + 2, (t + 2) % 3);

    __builtin_amdgcn_s_setprio(1);
#pragma unroll
    for (int m = 0; m < 4; ++m)
#pragma unroll
      for (int n = 0; n < 4; ++n)
        acc[m][n] = __builtin_amdgcn_mfma_f32_16x16x32_bf16(af[m], bfr[n], acc[m][n], 0, 0, 0);
    __builtin_amdgcn_s_setprio(0);
  }

  // Epilogue. C/D layout (m89): col = lane&15, row = (lane>>4)*4 + reg.
  const float* __restrict__ be = bias + (size_t)e * N;
  float* __restrict__ outF = (float*)Cv + (size_t)ks * Ttot * N;
  const int colBase = bcol + wc * 64 + lr;
  const int rowBase = wr * 64 + (lhi << 2);
#pragma unroll
  for (int n = 0; n < 4; ++n) {
    const int col = colBase + n * 16;
    const float bv = (SPLITK == 1 || ks == 0) ? be[col] : 0.0f;
#pragma unroll
    for (int m = 0; m < 4; ++m) {
      const int r0 = rowBase + m * 16;
#pragma unroll
      for (int j = 0; j < 4; ++j) {
        const int rr = r0 + j;
        if (rr < rows) {
          float v = acc[m][n][j] + bv;
          if (GELU) v = 0.5f * v * (1.0f + erff(v * 0.7071067811865476f));
          const size_t idx = (size_t)(row0 + rr) * N + col;
          if (OUTBF) ((unsigned short*)Cv)[idx] = f2bf(v);
          else       outF[idx] = v;
        }
      }
    }
  }
}

extern "C" void kernel_launch(void* const* d_in, const int* in_sizes, int n_in,
                              void* d_out, int out_size, void* d_ws, size_t ws_size,
                              hipStream_t stream) {
  const float* inp = (const float*)d_in[0];
  const float* w1  = (const float*)d_in[1];
  const float* b1  = (const float*)d_in[2];
  const float* w2  = (const float*)d_in[3];
  const float* b2  = (const float*)d_in[4];
  const int*   cnt = (const int*)d_in[5];

  const int E = in_sizes[5];
  const int H = in_sizes[2] / E;       // b1 is [E,H]
  const int D = in_sizes[4] / E;       // b2 is [E,D]
  const int T = in_sizes[0] / D;       // inp is [T,D]

  char* ws = (char*)d_ws;
  int4* tbl = (int4*)ws;               // <= 72 entries
  int* ntp = (int*)(ws + 2048);
  size_t off = 4096;
  unsigned short* inp_bf = (unsigned short*)(ws + off); off += (size_t)T * D * 2;
  unsigned short* w1_bf  = (unsigned short*)(ws + off); off += (size_t)E * H * D * 2;
  unsigned short* w2_bf  = (unsigned short*)(ws + off); off += (size_t)E * D * H * 2;
  unsigned short* h_bf   = (unsigned short*)(ws + off); off += (size_t)T * H * 2;
  // psum (2 x T*D f32 = 64 MB) overlays w1_bf (64 MB, dead after GEMM1).
  float* psum = (float*)w1_bf;
  (void)ws_size; (void)n_in; (void)out_size;

  build_tiles<<<1, 64, 0, stream>>>(cnt, E, tbl, ntp);

  cvt_kernel<<<2048, 256, 0, stream>>>(inp, inp_bf, (long)T * D);
  cvt_kernel<<<2048, 256, 0, stream>>>(w1, w1_bf, (long)E * H * D);
  cvt_kernel<<<2048, 256, 0, stream>>>(w2, w2_bf, (long)E * D * H);

  const int maxTiles = T / BM + E;
  // GEMM1: [T,D] x [E,H,D] -> h [T,H], +b1, gelu, bf16 out.
  dim3 g1(H / BN, maxTiles, 1);
  grouped_gemm<1, 1, 1><<<g1, 256, 0, stream>>>(inp_bf, w1_bf, b1, h_bf,
                                                tbl, ntp, H, D, T);
  // GEMM2: [T,H] x [E,D,H] -> psum[2][T,D] (bias in ks=0), split-K=2.
  dim3 g2(D / BN, maxTiles, 2);
  grouped_gemm<0, 0, 2><<<g2, 256, 0, stream>>>(h_bf, w2_bf, b2, psum,
                                                tbl, ntp, D, H, T);
  // out = psum0 + psum1
  combine_kernel<<<2048, 256, 0, stream>>>(psum, psum + (size_t)T * D,
                                           (float*)d_out, (long)T * D);
}

// Round 6
// 357.340 us; speedup vs baseline: 1.5365x; 1.0899x over previous
//
#include <hip/hip_runtime.h>
#include <hip/hip_bf16.h>
#include <cstdint>
#include <cstddef>

// MoE expert FFN: h = gelu(x @ w1[e]^T + b1[e]); out = h @ w2[e]^T + b2[e]
// R6: R1's proven 128x128 / 4-wave / BK=32 / 2-buffer syncthreads core, plus
// ONLY measurement-backed fixes:
//   (1) T2 LDS swizzle (R2: conflicts 8.4M -> 0; ~8.6% of CU cycles).
//   (2) Fast tanh-GELU instead of erff (R5: GEMM1 VALUBusy 37% vs GEMM2 11%
//       isolated the erff epilogue tail; tanh form is ~10 VALU/value,
//       |err| ~3e-4, far under the 7e-2 threshold and bf16 rounding noise).
//   (3) XCD chunking on GEMM2 ONLY (R4: GEMM2 FETCH 333->141 MB; GEMM1
//       regressed with chunking, so it keeps natural order).
//   (4) split-K=2 on GEMM2 (1152 blocks) + f32 combine pass.

typedef __bf16 bf16x8 __attribute__((ext_vector_type(8)));
typedef float f32x4 __attribute__((ext_vector_type(4)));
typedef unsigned short u16x8 __attribute__((ext_vector_type(8)));

#define BM 128
#define BN 128
#define BK 32

__device__ __forceinline__ unsigned short f2bf(float f) {
  unsigned u = __builtin_bit_cast(unsigned, f);
  u += 0x7FFFu + ((u >> 16) & 1u);   // RNE
  return (unsigned short)(u >> 16);
}

__device__ __forceinline__ float fast_gelu(float v) {
  // 0.5*v*(1+tanh(0.79788456*(v+0.044715*v^3))), tanh via exp.
  const float u = 0.7978845608028654f * (v + 0.044715f * v * v * v);
  const float t = 1.0f - 2.0f / (__expf(2.0f * u) + 1.0f);   // tanh(u)
  return 0.5f * v * (1.0f + t);
}

__device__ __forceinline__ void gload16(const void* g, void* lds) {
  __builtin_amdgcn_global_load_lds(
      (const __attribute__((address_space(1))) void*)g,
      (__attribute__((address_space(3))) void*)lds, 16, 0, 0);
}

// ---------------- setup: tile table (BM=128, shared) -------------------------
__global__ void build_tiles(const int* __restrict__ cnt, int E,
                            int4* __restrict__ tbl, int* __restrict__ ntp) {
  if (threadIdx.x == 0 && blockIdx.x == 0) {
    int nt = 0, start = 0;
    for (int e = 0; e < E; ++e) {
      int c = cnt[e];
      for (int t = 0; t < c; t += BM) {
        int4 v; v.x = e; v.y = start + t; v.z = (c - t < BM ? c - t : BM); v.w = 0;
        tbl[nt++] = v;
      }
      start += c;
    }
    *ntp = nt;
  }
}

// ---------------- f32 -> bf16 convert (vectorized) ---------------------------
__global__ void cvt_kernel(const float* __restrict__ src,
                           unsigned short* __restrict__ dst, long n) {
  long i = ((long)blockIdx.x * blockDim.x + threadIdx.x) * 8;
  const long stride = (long)gridDim.x * blockDim.x * 8;
  for (; i < n; i += stride) {
    float4 a = *reinterpret_cast<const float4*>(src + i);
    float4 b = *reinterpret_cast<const float4*>(src + i + 4);
    u16x8 o;
    o[0] = f2bf(a.x); o[1] = f2bf(a.y); o[2] = f2bf(a.z); o[3] = f2bf(a.w);
    o[4] = f2bf(b.x); o[5] = f2bf(b.y); o[6] = f2bf(b.z); o[7] = f2bf(b.w);
    *reinterpret_cast<u16x8*>(dst + i) = o;
  }
}

// ---------------- split-K combine: out = p0 + p1 (bias already in p0) --------
__global__ void combine_kernel(const float* __restrict__ p0,
                               const float* __restrict__ p1,
                               float* __restrict__ out, long n) {
  long i = ((long)blockIdx.x * blockDim.x + threadIdx.x) * 4;
  const long stride = (long)gridDim.x * blockDim.x * 4;
  for (; i < n; i += stride) {
    float4 a = *reinterpret_cast<const float4*>(p0 + i);
    float4 b = *reinterpret_cast<const float4*>(p1 + i);
    float4 o; o.x = a.x + b.x; o.y = a.y + b.y; o.z = a.z + b.z; o.w = a.w + b.w;
    *reinterpret_cast<float4*>(out + i) = o;
  }
}

// ---------------- grouped GEMM (R1 2-buffer core + swizzle) ------------------
// C[t,n] = A[t, ks*Kloc:(ks+1)*Kloc] . W[e][n, same] (+bias at ks==0, opt gelu)
template <int GELU, int OUTBF, int SPLITK, int CHUNK>
__global__ __launch_bounds__(256, 2) void grouped_gemm(
    const unsigned short* __restrict__ A, const unsigned short* __restrict__ W,
    const float* __restrict__ bias, void* __restrict__ Cv,
    const int4* __restrict__ tbl, const int* __restrict__ ntp,
    const int N, const int K, const int Ttot) {
  const int ks = (SPLITK > 1) ? blockIdx.z : 0;
  const int Kloc = K / SPLITK;

  int mt, bx;
  if (CHUNK) {
    // T1 bijective XCD chunking (m204): contiguous run of x-major order per XCD.
    const int gx = gridDim.x;
    const int nwg = gx * gridDim.y;
    const int flat = blockIdx.y * gx + blockIdx.x;
    const int q = nwg >> 3, r = nwg & 7, xc = flat & 7, dd = flat >> 3;
    const int orig = (xc < r ? xc * (q + 1) : r * (q + 1) + (xc - r) * q) + dd;
    mt = orig / gx;
    bx = orig - mt * gx;
  } else {
    mt = blockIdx.y;
    bx = blockIdx.x;
  }

  if (mt >= *ntp) return;
  const int4 ti = tbl[mt];
  const int e = ti.x, row0 = ti.y, rows = ti.z;
  const int bcol = bx * BN;

  __shared__ alignas(16) unsigned short sA[2][BM * BK];
  __shared__ alignas(16) unsigned short sB[2][BN * BK];

  const int tid = threadIdx.x;
  const int lane = tid & 63;
  const int wave = tid >> 6;
  const int wr = wave >> 1;  // 0..1
  const int wc = wave & 1;   // 0..1
  const int lr = lane & 15;
  const int lhi = lane >> 4; // 0..3

  const unsigned short* __restrict__ Aseg = A + (size_t)ks * Kloc;
  const unsigned short* __restrict__ Wexp = W + (size_t)e * N * K + (size_t)ks * Kloc;

  // Staging: dest row = wave*16 + (lane>>2) (+i*64), dest chunk = lane&3;
  // LDS byte = row*64 + chunk*16 == wave*1024 + lane*16 (linear, as gload_lds
  // requires). Source chunk = dest ^ ((row>>1)&3) — thread-constant, baked in.
  const int srow = wave * 16 + (lane >> 2);   // + i*64
  const int cg = (lane & 3) ^ ((srow >> 1) & 3);
  const int a0 = srow < rows ? srow : rows - 1;
  const int a1 = srow + 64 < rows ? srow + 64 : rows - 1;
  const unsigned short* gA0 = Aseg + (size_t)(row0 + a0) * K + cg * 8;
  const unsigned short* gA1 = Aseg + (size_t)(row0 + a1) * K + cg * 8;
  const unsigned short* gB0 = Wexp + (size_t)(bcol + srow) * K + cg * 8;
  const unsigned short* gB1 = Wexp + (size_t)(bcol + srow + 64) * K + cg * 8;

  f32x4 acc[4][4] = {};
  const int aRowB = wr * 64 + lr;
  const int bRowB = wc * 64 + lr;
  // Read-side swizzle term (row-term is lr-only: other row components %16==0).
  const int rsw = (lhi ^ ((lr >> 1) & 3)) * 8;

  const int nk = Kloc / BK;

  // prologue stage into buf 0
  {
    char* da = (char*)&sA[0][0] + wave * 1024;
    char* db = (char*)&sB[0][0] + wave * 1024;
    gload16(gA0, da);
    gload16(gA1, da + 4096);
    gload16(gB0, db);
    gload16(gB1, db + 4096);
  }
  __syncthreads();

  int buf = 0;
  for (int t = 0; t < nk; ++t) {
    if (t + 1 < nk) {
      const int k0 = (t + 1) * BK;
      char* da = (char*)&sA[buf ^ 1][0] + wave * 1024;
      char* db = (char*)&sB[buf ^ 1][0] + wave * 1024;
      gload16(gA0 + k0, da);
      gload16(gA1 + k0, da + 4096);
      gload16(gB0 + k0, db);
      gload16(gB1 + k0, db + 4096);
    }
    bf16x8 af[4], bfr[4];
#pragma unroll
    for (int m = 0; m < 4; ++m)
      af[m] = *reinterpret_cast<const bf16x8*>(&sA[buf][(aRowB + m * 16) * BK + rsw]);
#pragma unroll
    for (int n = 0; n < 4; ++n)
      bfr[n] = *reinterpret_cast<const bf16x8*>(&sB[buf][(bRowB + n * 16) * BK + rsw]);
#pragma unroll
    for (int m = 0; m < 4; ++m)
#pragma unroll
      for (int n = 0; n < 4; ++n)
        acc[m][n] = __builtin_amdgcn_mfma_f32_16x16x32_bf16(af[m], bfr[n], acc[m][n], 0, 0, 0);
    __syncthreads();
    buf ^= 1;
  }

  // Epilogue. C/D layout (m89): col = lane&15, row = (lane>>4)*4 + reg.
  const float* __restrict__ be = bias + (size_t)e * N;
  float* __restrict__ outF = (float*)Cv + (size_t)ks * Ttot * N;
  const int colBase = bcol + wc * 64 + lr;
  const int rowBase = wr * 64 + (lhi << 2);
#pragma unroll
  for (int n = 0; n < 4; ++n) {
    const int col = colBase + n * 16;
    const float bv = (SPLITK == 1 || ks == 0) ? be[col] : 0.0f;
#pragma unroll
    for (int m = 0; m < 4; ++m) {
      const int r0 = rowBase + m * 16;
#pragma unroll
      for (int j = 0; j < 4; ++j) {
        const int rr = r0 + j;
        if (rr < rows) {
          float v = acc[m][n][j] + bv;
          if (GELU) v = fast_gelu(v);
          const size_t idx = (size_t)(row0 + rr) * N + col;
          if (OUTBF) ((unsigned short*)Cv)[idx] = f2bf(v);
          else       outF[idx] = v;
        }
      }
    }
  }
}

extern "C" void kernel_launch(void* const* d_in, const int* in_sizes, int n_in,
                              void* d_out, int out_size, void* d_ws, size_t ws_size,
                              hipStream_t stream) {
  const float* inp = (const float*)d_in[0];
  const float* w1  = (const float*)d_in[1];
  const float* b1  = (const float*)d_in[2];
  const float* w2  = (const float*)d_in[3];
  const float* b2  = (const float*)d_in[4];
  const int*   cnt = (const int*)d_in[5];

  const int E = in_sizes[5];
  const int H = in_sizes[2] / E;       // b1 is [E,H]
  const int D = in_sizes[4] / E;       // b2 is [E,D]
  const int T = in_sizes[0] / D;       // inp is [T,D]

  char* ws = (char*)d_ws;
  int4* tbl = (int4*)ws;               // <= 72 entries
  int* ntp = (int*)(ws + 2048);
  size_t off = 4096;
  unsigned short* inp_bf = (unsigned short*)(ws + off); off += (size_t)T * D * 2;
  unsigned short* w1_bf  = (unsigned short*)(ws + off); off += (size_t)E * H * D * 2;
  unsigned short* w2_bf  = (unsigned short*)(ws + off); off += (size_t)E * D * H * 2;
  unsigned short* h_bf   = (unsigned short*)(ws + off); off += (size_t)T * H * 2;
  // psum (2 x T*D f32 = 64 MB) overlays w1_bf (64 MB, dead after GEMM1).
  float* psum = (float*)w1_bf;
  (void)ws_size; (void)n_in; (void)out_size;

  build_tiles<<<1, 64, 0, stream>>>(cnt, E, tbl, ntp);

  cvt_kernel<<<2048, 256, 0, stream>>>(inp, inp_bf, (long)T * D);
  cvt_kernel<<<2048, 256, 0, stream>>>(w1, w1_bf, (long)E * H * D);
  cvt_kernel<<<2048, 256, 0, stream>>>(w2, w2_bf, (long)E * D * H);

  const int maxTiles = T / BM + E;
  // GEMM1: [T,D] x [E,H,D] -> h [T,H], +b1, fast-gelu, bf16 out. Natural order.
  dim3 g1(H / BN, maxTiles, 1);
  grouped_gemm<1, 1, 1, 0><<<g1, 256, 0, stream>>>(inp_bf, w1_bf, b1, h_bf,
                                                   tbl, ntp, H, D, T);
  // GEMM2: [T,H] x [E,D,H] -> psum[2][T,D] (bias in ks=0), split-K=2, chunked.
  dim3 g2(D / BN, maxTiles, 2);
  grouped_gemm<0, 0, 2, 1><<<g2, 256, 0, stream>>>(h_bf, w2_bf, b2, psum,
                                                   tbl, ntp, D, H, T);
  // out = psum0 + psum1
  combine_kernel<<<2048, 256, 0, stream>>>(psum, psum + (size_t)T * D,
                                           (float*)d_out, (long)T * D);
}

// Round 7
// 356.851 us; speedup vs baseline: 1.5386x; 1.0014x over previous
//
#include <hip/hip_runtime.h>
#include <hip/hip_bf16.h>
#include <cstdint>
#include <cstddef>

// MoE expert FFN: h = gelu(x @ w1[e]^T + b1[e]); out = h @ w2[e]^T + b2[e]
// R7: faithful m201-style 8-phase 256x256 / BK=64 / 8-wave schedule.
//   LDS 128KB: buf0/buf1, each = A[256][64] + B[256][64] bf16, chunk-XOR
//   swizzled (c ^= row&7, inverse-applied on global source; linear dest as
//   global_load_lds requires). Half-tile (128 rows, 16KB) = stage unit =
//   2 gload16/thread. Per K-tile pair (2x64), 8 phases:
//     P0 ds A0,B0(buf0)[12]  stage (2t+1).B1->buf1
//     P1 ds A1(buf0)[8]      stage (2t+2).A0->buf0
//     P2 ds B1(buf0)[4]      stage (2t+2).B0->buf0
//     P3 --                  stage (2t+2).A1->buf0   + vmcnt(6) before BAR
//     P4 ds A0,B0(buf1)      stage (2t+2).B1->buf0
//     P5 ds A1(buf1)         stage (2t+3).A0->buf1
//     P6 ds B1(buf1)         stage (2t+3).B0->buf1
//     P7 --                  stage (2t+3).A1->buf1   + vmcnt(6) before BAR
//   each phase: {ds|stage} BAR lgkmcnt(0) setprio1 16xMFMA setprio0 BAR.
//   vmcnt(6)=3 halves outstanding: at P3 the 6 newest loads are P1,P2,P3's ->
//   (2t+1).B1 landed -> buf1 complete before P4 reads it (after P3's BAR).
//   At P7 -> (2t+2).B1 landed -> buf0 complete for next P0. Prologue stages
//   7 halves + vmcnt(6) + BAR (tile0's 4 halves proven landed).

typedef __bf16 bf16x8 __attribute__((ext_vector_type(8)));
typedef float f32x4 __attribute__((ext_vector_type(4)));
typedef unsigned short u16x8 __attribute__((ext_vector_type(8)));

__device__ __forceinline__ unsigned short f2bf(float f) {
  unsigned u = __builtin_bit_cast(unsigned, f);
  u += 0x7FFFu + ((u >> 16) & 1u);   // RNE
  return (unsigned short)(u >> 16);
}

__device__ __forceinline__ float fast_gelu(float v) {
  const float u = 0.7978845608028654f * (v + 0.044715f * v * v * v);
  const float t = 1.0f - 2.0f / (__expf(2.0f * u) + 1.0f);   // tanh(u)
  return 0.5f * v * (1.0f + t);
}

__device__ __forceinline__ void gload16(const void* g, void* lds) {
  __builtin_amdgcn_global_load_lds(
      (const __attribute__((address_space(1))) void*)g,
      (__attribute__((address_space(3))) void*)lds, 16, 0, 0);
}

#define BAR() __builtin_amdgcn_s_barrier()
#define WAIT_LGKM0() asm volatile("s_waitcnt lgkmcnt(0)" ::: "memory")
#define WAIT_VM6() asm volatile("s_waitcnt vmcnt(6)" ::: "memory")

// ---------------- setup: tile table (BM=256) ---------------------------------
__global__ void build_tiles(const int* __restrict__ cnt, int E,
                            int4* __restrict__ tbl, int* __restrict__ ntp) {
  if (threadIdx.x == 0 && blockIdx.x == 0) {
    int nt = 0, start = 0;
    for (int e = 0; e < E; ++e) {
      int c = cnt[e];
      for (int t = 0; t < c; t += 256) {
        int4 v; v.x = e; v.y = start + t; v.z = (c - t < 256 ? c - t : 256); v.w = 0;
        tbl[nt++] = v;
      }
      start += c;
    }
    *ntp = nt;
  }
}

// ---------------- f32 -> bf16 convert (vectorized) ---------------------------
__global__ void cvt_kernel(const float* __restrict__ src,
                           unsigned short* __restrict__ dst, long n) {
  long i = ((long)blockIdx.x * blockDim.x + threadIdx.x) * 8;
  const long stride = (long)gridDim.x * blockDim.x * 8;
  for (; i < n; i += stride) {
    float4 a = *reinterpret_cast<const float4*>(src + i);
    float4 b = *reinterpret_cast<const float4*>(src + i + 4);
    u16x8 o;
    o[0] = f2bf(a.x); o[1] = f2bf(a.y); o[2] = f2bf(a.z); o[3] = f2bf(a.w);
    o[4] = f2bf(b.x); o[5] = f2bf(b.y); o[6] = f2bf(b.z); o[7] = f2bf(b.w);
    *reinterpret_cast<u16x8*>(dst + i) = o;
  }
}

// ---------------- split-K combine: out = p0 + p1 (bias already in p0) --------
__global__ void combine_kernel(const float* __restrict__ p0,
                               const float* __restrict__ p1,
                               float* __restrict__ out, long n) {
  long i = ((long)blockIdx.x * blockDim.x + threadIdx.x) * 4;
  const long stride = (long)gridDim.x * blockDim.x * 4;
  for (; i < n; i += stride) {
    float4 a = *reinterpret_cast<const float4*>(p0 + i);
    float4 b = *reinterpret_cast<const float4*>(p1 + i);
    float4 o; o.x = a.x + b.x; o.y = a.y + b.y; o.z = a.z + b.z; o.w = a.w + b.w;
    *reinterpret_cast<float4*>(out + i) = o;
  }
}

// ---------------- grouped GEMM, 8-phase 256^2 --------------------------------
// C[t,n] = A[t, ks*Kloc:(ks+1)*Kloc] . W[e][n, same] (+bias at ks==0, opt gelu)
// A:[T,K] bf16, W:[E,N,K] bf16. 512 thr / 8 waves (2M x 4N); per-wave C 128x64.
template <int GELU, int OUTBF, int SPLITK, int CHUNK>
__global__ __launch_bounds__(512, 2) void gemm8p(
    const unsigned short* __restrict__ A, const unsigned short* __restrict__ W,
    const float* __restrict__ bias, void* __restrict__ Cv,
    const int4* __restrict__ tbl, const int* __restrict__ ntp,
    const int N, const int K, const int Ttot) {
  const int ks = (SPLITK > 1) ? blockIdx.z : 0;
  const int Kloc = K / SPLITK;

  int mt, bx;
  if (CHUNK) {
    const int gx = gridDim.x;
    const int nwg = gx * gridDim.y;
    const int flat = blockIdx.y * gx + blockIdx.x;
    const int q = nwg >> 3, r = nwg & 7, xc = flat & 7, dd = flat >> 3;
    const int orig = (xc < r ? xc * (q + 1) : r * (q + 1) + (xc - r) * q) + dd;
    mt = orig / gx;
    bx = orig - mt * gx;
  } else {
    mt = blockIdx.y;
    bx = blockIdx.x;
  }
  if (mt >= *ntp) return;
  const int4 ti = tbl[mt];
  const int e = ti.x, row0 = ti.y, rows = ti.z;
  const int bcol = bx * 256;

  // LDS: buf*65536 | (isB)*32768 | half*16384 ; row stride 128 B, 8x16B chunks.
  __shared__ alignas(16) char smem[131072];

  const int tid = threadIdx.x;
  const int lane = tid & 63;
  const int wave = tid >> 6;
  const int wr = wave >> 2;   // 0..1 -> rows wr*128
  const int wc = wave & 3;    // 0..3 -> cols wc*64
  const int lr = lane & 15;
  const int lhi = lane >> 4;  // 0..3

  // ---- staging source pointers (thread-constant, inverse-swizzled) ----------
  // dest (linear): half + i*8192 + wave*1024 + lane*16 -> row = i*64+wave*8+
  // (lane>>3), chunk = lane&7. source chunk = (lane&7) ^ (row&7).
  const int hrow = wave * 8 + (lane >> 3);            // 0..63 (+i*64, +h*128)
  const int csrc = ((lane & 7) ^ (hrow & 7)) * 8;     // shorts
  const unsigned short* pS[4][2];  // [which: 0=A0,1=A1,2=B0,3=B1][round i]
#pragma unroll
  for (int h = 0; h < 2; ++h)
#pragma unroll
    for (int i = 0; i < 2; ++i) {
      const int rA = h * 128 + i * 64 + hrow;
      const int rcA = rA < rows ? rA : rows - 1;      // clamp inside segment
      pS[h][i] = A + (size_t)ks * Kloc + (size_t)(row0 + rcA) * K + csrc;
      pS[2 + h][i] =
          W + ((size_t)e * N + bcol + h * 128 + i * 64 + hrow) * K +
          (size_t)ks * Kloc + csrc;
    }

  auto STG = [&](int kt, int buf, int which) {
    char* d = smem + buf * 65536 + (which >> 1) * 32768 + (which & 1) * 16384 +
              wave * 1024;
    gload16(pS[which][0] + kt * 64, d);
    gload16(pS[which][1] + kt * 64, d + 8192);
  };

  // ---- LDS read addressing (swizzled) ---------------------------------------
  const int sw0 = ((lhi ^ (lr & 7)) * 16);            // kstep 0
  const int sw1 = (((4 | lhi) ^ (lr & 7)) * 16);      // kstep 1
  const int rbA = (wr * 128 + lr) * 128;
  const int rbB = 32768 + (wc * 64 + lr) * 128;

  bf16x8 a0F[8], a1F[8], b0F[4], b1F[4];
  f32x4 acc[8][4] = {};

  auto LDA = [&](int buf, int mh, bf16x8* dst) {
#pragma unroll
    for (int mm = 0; mm < 4; ++mm) {
      const char* p = smem + buf * 65536 + rbA + (mh * 4 + mm) * 2048;
      dst[mm * 2 + 0] = *(const bf16x8*)(p + sw0);
      dst[mm * 2 + 1] = *(const bf16x8*)(p + sw1);
    }
  };
  auto LDB = [&](int buf, int nh, bf16x8* dst) {
#pragma unroll
    for (int nn = 0; nn < 2; ++nn) {
      const char* p = smem + buf * 65536 + rbB + (nh * 2 + nn) * 2048;
      dst[nn * 2 + 0] = *(const bf16x8*)(p + sw0);
      dst[nn * 2 + 1] = *(const bf16x8*)(p + sw1);
    }
  };
  auto MMA = [&](const bf16x8* Af, const bf16x8* Bf, int mb, int nb) {
    __builtin_amdgcn_s_setprio(1);
#pragma unroll
    for (int mm = 0; mm < 4; ++mm)
#pragma unroll
      for (int nn = 0; nn < 2; ++nn) {
        acc[mb + mm][nb + nn] = __builtin_amdgcn_mfma_f32_16x16x32_bf16(
            Af[mm * 2 + 0], Bf[nn * 2 + 0], acc[mb + mm][nb + nn], 0, 0, 0);
        acc[mb + mm][nb + nn] = __builtin_amdgcn_mfma_f32_16x16x32_bf16(
            Af[mm * 2 + 1], Bf[nn * 2 + 1], acc[mb + mm][nb + nn], 0, 0, 0);
      }
    __builtin_amdgcn_s_setprio(0);
  };

  const int nk = Kloc / 64;          // even (>=16) for all shapes here
  // ---- prologue: 7 halves, stream order; vmcnt(6) => tile0 fully landed -----
  STG(0, 0, 0); STG(0, 0, 2); STG(0, 0, 1); STG(0, 0, 3);
  STG(1, 1, 0); STG(1, 1, 2); STG(1, 1, 1);
  WAIT_VM6();
  BAR();

  const int nIter = nk >> 1;
  for (int t = 0; t < nIter; ++t) {
    const int k1 = 2 * t + 1;
    const int k2 = (2 * t + 2 < nk) ? 2 * t + 2 : nk - 1;   // clamped dup-stage
    const int k3 = (2 * t + 3 < nk) ? 2 * t + 3 : nk - 1;   // keeps vmcnt exact
    // P0
    LDA(0, 0, a0F); LDB(0, 0, b0F);
    STG(k1, 1, 3);
    BAR(); WAIT_LGKM0();
    MMA(a0F, b0F, 0, 0);
    BAR();
    // P1
    LDA(0, 1, a1F);
    STG(k2, 0, 0);
    BAR(); WAIT_LGKM0();
    MMA(a1F, b0F, 4, 0);
    BAR();
    // P2
    LDB(0, 1, b1F);
    STG(k2, 0, 2);
    BAR(); WAIT_LGKM0();
    MMA(a0F, b1F, 0, 2);
    BAR();
    // P3
    STG(k2, 0, 1);
    WAIT_VM6();                      // (2t+1).B1 landed -> buf1 complete
    BAR(); WAIT_LGKM0();
    MMA(a1F, b1F, 4, 2);
    BAR();
    // P4
    LDA(1, 0, a0F); LDB(1, 0, b0F);
    STG(k2, 0, 3);
    BAR(); WAIT_LGKM0();
    MMA(a0F, b0F, 0, 0);
    BAR();
    // P5
    LDA(1, 1, a1F);
    STG(k3, 1, 0);
    BAR(); WAIT_LGKM0();
    MMA(a1F, b0F, 4, 0);
    BAR();
    // P6
    LDB(1, 1, b1F);
    STG(k3, 1, 2);
    BAR(); WAIT_LGKM0();
    MMA(a0F, b1F, 0, 2);
    BAR();
    // P7
    STG(k3, 1, 1);
    WAIT_VM6();                      // (2t+2).B1 landed -> buf0 complete
    BAR(); WAIT_LGKM0();
    MMA(a1F, b1F, 4, 2);
    BAR();
  }
  asm volatile("s_waitcnt vmcnt(0)" ::: "memory");   // retire dangling stages

  // ---- epilogue. C/D layout (m89): col = lane&15, row = (lane>>4)*4 + reg ---
  const float* __restrict__ be = bias + (size_t)e * N;
  float* __restrict__ outF = (float*)Cv + (size_t)ks * Ttot * N;
#pragma unroll
  for (int n = 0; n < 4; ++n) {
    const int col = bcol + wc * 64 + n * 16 + lr;
    const float bv = (SPLITK == 1 || ks == 0) ? be[col] : 0.0f;
#pragma unroll
    for (int m = 0; m < 8; ++m) {
      const int r0 = wr * 128 + m * 16 + (lhi << 2);
#pragma unroll
      for (int j = 0; j < 4; ++j) {
        const int rr = r0 + j;
        if (rr < rows) {
          float v = acc[m][n][j] + bv;
          if (GELU) v = fast_gelu(v);
          const size_t idx = (size_t)(row0 + rr) * N + col;
          if (OUTBF) ((unsigned short*)Cv)[idx] = f2bf(v);
          else       outF[idx] = v;
        }
      }
    }
  }
}

extern "C" void kernel_launch(void* const* d_in, const int* in_sizes, int n_in,
                              void* d_out, int out_size, void* d_ws, size_t ws_size,
                              hipStream_t stream) {
  const float* inp = (const float*)d_in[0];
  const float* w1  = (const float*)d_in[1];
  const float* b1  = (const float*)d_in[2];
  const float* w2  = (const float*)d_in[3];
  const float* b2  = (const float*)d_in[4];
  const int*   cnt = (const int*)d_in[5];

  const int E = in_sizes[5];
  const int H = in_sizes[2] / E;       // b1 is [E,H]
  const int D = in_sizes[4] / E;       // b2 is [E,D]
  const int T = in_sizes[0] / D;       // inp is [T,D]

  char* ws = (char*)d_ws;
  int4* tbl = (int4*)ws;               // <= 40 entries
  int* ntp = (int*)(ws + 2048);
  size_t off = 4096;
  unsigned short* inp_bf = (unsigned short*)(ws + off); off += (size_t)T * D * 2;
  unsigned short* w1_bf  = (unsigned short*)(ws + off); off += (size_t)E * H * D * 2;
  unsigned short* w2_bf  = (unsigned short*)(ws + off); off += (size_t)E * D * H * 2;
  unsigned short* h_bf   = (unsigned short*)(ws + off); off += (size_t)T * H * 2;
  // psum (2 x T*D f32 = 64 MB) overlays w1_bf (64 MB, dead after GEMM1).
  float* psum = (float*)w1_bf;
  (void)ws_size; (void)n_in; (void)out_size;

  build_tiles<<<1, 64, 0, stream>>>(cnt, E, tbl, ntp);

  cvt_kernel<<<2048, 256, 0, stream>>>(inp, inp_bf, (long)T * D);
  cvt_kernel<<<2048, 256, 0, stream>>>(w1, w1_bf, (long)E * H * D);
  cvt_kernel<<<2048, 256, 0, stream>>>(w2, w2_bf, (long)E * D * H);

  const int maxTiles = T / 256 + E;
  // GEMM1: [T,D] x [E,H,D] -> h [T,H], +b1, fast-gelu, bf16. Natural order.
  dim3 g1(H / 256, maxTiles, 1);
  gemm8p<1, 1, 1, 0><<<g1, 512, 0, stream>>>(inp_bf, w1_bf, b1, h_bf,
                                             tbl, ntp, H, D, T);
  // GEMM2: [T,H] x [E,D,H] -> psum[2][T,D] (bias in ks=0), split-K=2, chunked.
  dim3 g2(D / 256, maxTiles, 2);
  gemm8p<0, 0, 2, 1><<<g2, 512, 0, stream>>>(h_bf, w2_bf, b2, psum,
                                             tbl, ntp, D, H, T);
  // out = psum0 + psum1
  combine_kernel<<<2048, 256, 0, stream>>>(psum, psum + (size_t)T * D,
                                           (float*)d_out, (long)T * D);
}

// Round 8
// 349.421 us; speedup vs baseline: 1.5713x; 1.0213x over previous
//
#include <hip/hip_runtime.h>
#include <hip/hip_bf16.h>
#include <cstdint>
#include <cstddef>

// MoE expert FFN: h = gelu(x @ w1[e]^T + b1[e]); out = h @ w2[e]^T + b2[e]
// R8: consolidation round. Seven structures measured; all GEMM schedules tie at
// ~140-160us (MfmaUtil 18-20%). Lock the best-measured total configuration:
//   - R1/R6 128x128 / 4-wave / BK=32 / 2-buffer syncthreads GEMM core
//   - T2 LDS swizzle (R2-verified 0 bank conflicts)
//   - fast tanh-GELU (R6-verified: VALUBusy 37% -> 10%)
//   - natural block order BOTH GEMMs (R4: XCD chunk regressed G1; R1 natural
//     G2 = 146us best), NO split-K, NO combine (saves ~15us + 96MB traffic)
//   - NEW isolated lever: __launch_bounds__(256, 4) — LDS(32KB) allows 5
//     blocks/CU but measured occupancy stuck at ~2.5; test allocator vs
//     dispatcher as the residency limit.

typedef __bf16 bf16x8 __attribute__((ext_vector_type(8)));
typedef float f32x4 __attribute__((ext_vector_type(4)));
typedef unsigned short u16x8 __attribute__((ext_vector_type(8)));

#define BM 128
#define BN 128
#define BK 32

__device__ __forceinline__ unsigned short f2bf(float f) {
  unsigned u = __builtin_bit_cast(unsigned, f);
  u += 0x7FFFu + ((u >> 16) & 1u);   // RNE
  return (unsigned short)(u >> 16);
}

__device__ __forceinline__ float fast_gelu(float v) {
  const float u = 0.7978845608028654f * (v + 0.044715f * v * v * v);
  const float t = 1.0f - 2.0f / (__expf(2.0f * u) + 1.0f);   // tanh(u)
  return 0.5f * v * (1.0f + t);
}

__device__ __forceinline__ void gload16(const void* g, void* lds) {
  __builtin_amdgcn_global_load_lds(
      (const __attribute__((address_space(1))) void*)g,
      (__attribute__((address_space(3))) void*)lds, 16, 0, 0);
}

// ---------------- setup: tile table (BM=128, shared) -------------------------
__global__ void build_tiles(const int* __restrict__ cnt, int E,
                            int4* __restrict__ tbl, int* __restrict__ ntp) {
  if (threadIdx.x == 0 && blockIdx.x == 0) {
    int nt = 0, start = 0;
    for (int e = 0; e < E; ++e) {
      int c = cnt[e];
      for (int t = 0; t < c; t += BM) {
        int4 v; v.x = e; v.y = start + t; v.z = (c - t < BM ? c - t : BM); v.w = 0;
        tbl[nt++] = v;
      }
      start += c;
    }
    *ntp = nt;
  }
}

// ---------------- f32 -> bf16 convert (vectorized) ---------------------------
__global__ void cvt_kernel(const float* __restrict__ src,
                           unsigned short* __restrict__ dst, long n) {
  long i = ((long)blockIdx.x * blockDim.x + threadIdx.x) * 8;
  const long stride = (long)gridDim.x * blockDim.x * 8;
  for (; i < n; i += stride) {
    float4 a = *reinterpret_cast<const float4*>(src + i);
    float4 b = *reinterpret_cast<const float4*>(src + i + 4);
    u16x8 o;
    o[0] = f2bf(a.x); o[1] = f2bf(a.y); o[2] = f2bf(a.z); o[3] = f2bf(a.w);
    o[4] = f2bf(b.x); o[5] = f2bf(b.y); o[6] = f2bf(b.z); o[7] = f2bf(b.w);
    *reinterpret_cast<u16x8*>(dst + i) = o;
  }
}

// ---------------- grouped GEMM (128x128, 4 waves, 2-buffer) ------------------
// C[t,n] = A[t,:] . W[e][n,:] (+bias, opt gelu). A:[T,K] bf16, W:[E,N,K] bf16.
template <int GELU, int OUTBF>
__global__ __launch_bounds__(256, 4) void grouped_gemm(
    const unsigned short* __restrict__ A, const unsigned short* __restrict__ W,
    const float* __restrict__ bias, void* __restrict__ Cv,
    const int4* __restrict__ tbl, const int* __restrict__ ntp,
    const int N, const int K) {
  const int mt = blockIdx.y;
  const int bx = blockIdx.x;
  if (mt >= *ntp) return;
  const int4 ti = tbl[mt];
  const int e = ti.x, row0 = ti.y, rows = ti.z;
  const int bcol = bx * BN;

  __shared__ alignas(16) unsigned short sA[2][BM * BK];
  __shared__ alignas(16) unsigned short sB[2][BN * BK];

  const int tid = threadIdx.x;
  const int lane = tid & 63;
  const int wave = tid >> 6;
  const int wr = wave >> 1;  // 0..1
  const int wc = wave & 1;   // 0..1
  const int lr = lane & 15;
  const int lhi = lane >> 4; // 0..3

  const unsigned short* __restrict__ Wexp = W + (size_t)e * N * K;

  // Staging: dest row = wave*16 + (lane>>2) (+i*64), dest chunk = lane&3;
  // LDS byte = row*64 + chunk*16 == wave*1024 + lane*16 (linear, as gload_lds
  // requires). Source chunk = dest ^ ((row>>1)&3) — thread-constant, baked in.
  const int srow = wave * 16 + (lane >> 2);   // + i*64
  const int cg = (lane & 3) ^ ((srow >> 1) & 3);
  const int a0 = srow < rows ? srow : rows - 1;
  const int a1 = srow + 64 < rows ? srow + 64 : rows - 1;
  const unsigned short* gA0 = A + (size_t)(row0 + a0) * K + cg * 8;
  const unsigned short* gA1 = A + (size_t)(row0 + a1) * K + cg * 8;
  const unsigned short* gB0 = Wexp + (size_t)(bcol + srow) * K + cg * 8;
  const unsigned short* gB1 = Wexp + (size_t)(bcol + srow + 64) * K + cg * 8;

  f32x4 acc[4][4] = {};
  const int aRowB = wr * 64 + lr;
  const int bRowB = wc * 64 + lr;
  // Read-side swizzle term (row-term is lr-only: other row components %16==0).
  const int rsw = (lhi ^ ((lr >> 1) & 3)) * 8;

  const int nk = K / BK;

  // prologue stage into buf 0
  {
    char* da = (char*)&sA[0][0] + wave * 1024;
    char* db = (char*)&sB[0][0] + wave * 1024;
    gload16(gA0, da);
    gload16(gA1, da + 4096);
    gload16(gB0, db);
    gload16(gB1, db + 4096);
  }
  __syncthreads();

  int buf = 0;
  for (int t = 0; t < nk; ++t) {
    if (t + 1 < nk) {
      const int k0 = (t + 1) * BK;
      char* da = (char*)&sA[buf ^ 1][0] + wave * 1024;
      char* db = (char*)&sB[buf ^ 1][0] + wave * 1024;
      gload16(gA0 + k0, da);
      gload16(gA1 + k0, da + 4096);
      gload16(gB0 + k0, db);
      gload16(gB1 + k0, db + 4096);
    }
    bf16x8 af[4], bfr[4];
#pragma unroll
    for (int m = 0; m < 4; ++m)
      af[m] = *reinterpret_cast<const bf16x8*>(&sA[buf][(aRowB + m * 16) * BK + rsw]);
#pragma unroll
    for (int n = 0; n < 4; ++n)
      bfr[n] = *reinterpret_cast<const bf16x8*>(&sB[buf][(bRowB + n * 16) * BK + rsw]);
#pragma unroll
    for (int m = 0; m < 4; ++m)
#pragma unroll
      for (int n = 0; n < 4; ++n)
        acc[m][n] = __builtin_amdgcn_mfma_f32_16x16x32_bf16(af[m], bfr[n], acc[m][n], 0, 0, 0);
    __syncthreads();
    buf ^= 1;
  }

  // Epilogue. C/D layout (m89): col = lane&15, row = (lane>>4)*4 + reg.
  const float* __restrict__ be = bias + (size_t)e * N;
  const int colBase = bcol + wc * 64 + lr;
  const int rowBase = wr * 64 + (lhi << 2);
#pragma unroll
  for (int n = 0; n < 4; ++n) {
    const int col = colBase + n * 16;
    const float bv = be[col];
#pragma unroll
    for (int m = 0; m < 4; ++m) {
      const int r0 = rowBase + m * 16;
#pragma unroll
      for (int j = 0; j < 4; ++j) {
        const int rr = r0 + j;
        if (rr < rows) {
          float v = acc[m][n][j] + bv;
          if (GELU) v = fast_gelu(v);
          const size_t idx = (size_t)(row0 + rr) * N + col;
          if (OUTBF) ((unsigned short*)Cv)[idx] = f2bf(v);
          else       ((float*)Cv)[idx] = v;
        }
      }
    }
  }
}

extern "C" void kernel_launch(void* const* d_in, const int* in_sizes, int n_in,
                              void* d_out, int out_size, void* d_ws, size_t ws_size,
                              hipStream_t stream) {
  const float* inp = (const float*)d_in[0];
  const float* w1  = (const float*)d_in[1];
  const float* b1  = (const float*)d_in[2];
  const float* w2  = (const float*)d_in[3];
  const float* b2  = (const float*)d_in[4];
  const int*   cnt = (const int*)d_in[5];

  const int E = in_sizes[5];
  const int H = in_sizes[2] / E;       // b1 is [E,H]
  const int D = in_sizes[4] / E;       // b2 is [E,D]
  const int T = in_sizes[0] / D;       // inp is [T,D]

  char* ws = (char*)d_ws;
  int4* tbl = (int4*)ws;               // <= 72 entries
  int* ntp = (int*)(ws + 2048);
  size_t off = 4096;
  unsigned short* inp_bf = (unsigned short*)(ws + off); off += (size_t)T * D * 2;
  unsigned short* w1_bf  = (unsigned short*)(ws + off); off += (size_t)E * H * D * 2;
  unsigned short* w2_bf  = (unsigned short*)(ws + off); off += (size_t)E * D * H * 2;
  unsigned short* h_bf   = (unsigned short*)(ws + off); off += (size_t)T * H * 2;
  (void)ws_size; (void)n_in; (void)out_size;

  build_tiles<<<1, 64, 0, stream>>>(cnt, E, tbl, ntp);

  cvt_kernel<<<2048, 256, 0, stream>>>(inp, inp_bf, (long)T * D);
  cvt_kernel<<<2048, 256, 0, stream>>>(w1, w1_bf, (long)E * H * D);
  cvt_kernel<<<2048, 256, 0, stream>>>(w2, w2_bf, (long)E * D * H);

  const int maxTiles = T / BM + E;
  // GEMM1: [T,D] x [E,H,D] -> h [T,H], +b1, fast-gelu, bf16 out.
  dim3 g1(H / BN, maxTiles);
  grouped_gemm<1, 1><<<g1, 256, 0, stream>>>(inp_bf, w1_bf, b1, h_bf,
                                             tbl, ntp, H, D);
  // GEMM2: [T,H] x [E,D,H] -> out [T,D] f32, direct.
  dim3 g2(D / BN, maxTiles);
  grouped_gemm<0, 0><<<g2, 256, 0, stream>>>(h_bf, w2_bf, b2, d_out,
                                             tbl, ntp, D, H);
}

// Round 9
// 347.146 us; speedup vs baseline: 1.5816x; 1.0066x over previous
//
#include <hip/hip_runtime.h>
#include <hip/hip_bf16.h>
#include <cstdint>
#include <cstddef>

// MoE expert FFN: h = gelu(x @ w1[e]^T + b1[e]); out = h @ w2[e]^T + b2[e]
// R9: R8 locked config (128x128 / 4-wave / BK=32 / 2-buffer, T2 swizzle,
// fast-gelu, natural order, no split-K) with ONE change: 16x16x32 MFMA ->
// 32x32x16 MFMA (same LDS bytes, same ds_read count; 64.6 vs 77.6 matrix-pipe
// cyc per K-step, half the MFMA instruction issues; ubench 2495 vs 2075 TF).
//   A/B operand: row = lane&31, k = (lane>>5)*8 + i  (analog of validated
//   16x16x32 rule).  C/D (m74/m101-verified): col = lane&31,
//   row = (reg&3) + 8*(reg>>2) + 4*(lane>>5).

typedef __bf16 bf16x8 __attribute__((ext_vector_type(8)));
typedef float f32x16 __attribute__((ext_vector_type(16)));
typedef unsigned short u16x8 __attribute__((ext_vector_type(8)));

#define BM 128
#define BN 128
#define BK 32

__device__ __forceinline__ unsigned short f2bf(float f) {
  unsigned u = __builtin_bit_cast(unsigned, f);
  u += 0x7FFFu + ((u >> 16) & 1u);   // RNE
  return (unsigned short)(u >> 16);
}

__device__ __forceinline__ float fast_gelu(float v) {
  const float u = 0.7978845608028654f * (v + 0.044715f * v * v * v);
  const float t = 1.0f - 2.0f / (__expf(2.0f * u) + 1.0f);   // tanh(u)
  return 0.5f * v * (1.0f + t);
}

__device__ __forceinline__ void gload16(const void* g, void* lds) {
  __builtin_amdgcn_global_load_lds(
      (const __attribute__((address_space(1))) void*)g,
      (__attribute__((address_space(3))) void*)lds, 16, 0, 0);
}

// ---------------- setup: tile table (BM=128, shared) -------------------------
__global__ void build_tiles(const int* __restrict__ cnt, int E,
                            int4* __restrict__ tbl, int* __restrict__ ntp) {
  if (threadIdx.x == 0 && blockIdx.x == 0) {
    int nt = 0, start = 0;
    for (int e = 0; e < E; ++e) {
      int c = cnt[e];
      for (int t = 0; t < c; t += BM) {
        int4 v; v.x = e; v.y = start + t; v.z = (c - t < BM ? c - t : BM); v.w = 0;
        tbl[nt++] = v;
      }
      start += c;
    }
    *ntp = nt;
  }
}

// ---------------- f32 -> bf16 convert (vectorized) ---------------------------
__global__ void cvt_kernel(const float* __restrict__ src,
                           unsigned short* __restrict__ dst, long n) {
  long i = ((long)blockIdx.x * blockDim.x + threadIdx.x) * 8;
  const long stride = (long)gridDim.x * blockDim.x * 8;
  for (; i < n; i += stride) {
    float4 a = *reinterpret_cast<const float4*>(src + i);
    float4 b = *reinterpret_cast<const float4*>(src + i + 4);
    u16x8 o;
    o[0] = f2bf(a.x); o[1] = f2bf(a.y); o[2] = f2bf(a.z); o[3] = f2bf(a.w);
    o[4] = f2bf(b.x); o[5] = f2bf(b.y); o[6] = f2bf(b.z); o[7] = f2bf(b.w);
    *reinterpret_cast<u16x8*>(dst + i) = o;
  }
}

// ---------------- grouped GEMM (128x128, 4 waves, 2-buffer, 32x32 MFMA) ------
// C[t,n] = A[t,:] . W[e][n,:] (+bias, opt gelu). A:[T,K] bf16, W:[E,N,K] bf16.
template <int GELU, int OUTBF>
__global__ __launch_bounds__(256, 4) void grouped_gemm(
    const unsigned short* __restrict__ A, const unsigned short* __restrict__ W,
    const float* __restrict__ bias, void* __restrict__ Cv,
    const int4* __restrict__ tbl, const int* __restrict__ ntp,
    const int N, const int K) {
  const int mt = blockIdx.y;
  const int bx = blockIdx.x;
  if (mt >= *ntp) return;
  const int4 ti = tbl[mt];
  const int e = ti.x, row0 = ti.y, rows = ti.z;
  const int bcol = bx * BN;

  __shared__ alignas(16) unsigned short sA[2][BM * BK];
  __shared__ alignas(16) unsigned short sB[2][BN * BK];

  const int tid = threadIdx.x;
  const int lane = tid & 63;
  const int wave = tid >> 6;
  const int wr = wave >> 1;   // 0..1
  const int wc = wave & 1;    // 0..1
  const int lr32 = lane & 31; // operand row within 32
  const int l5 = lane >> 5;   // k-half-of-16 selector

  const unsigned short* __restrict__ Wexp = W + (size_t)e * N * K;

  // Staging (unchanged from R8): dest row = wave*16 + (lane>>2) (+i*64),
  // dest chunk = lane&3; LDS byte = wave*1024 + lane*16 (linear). Source
  // chunk = dest ^ ((row>>1)&3) — thread-constant.
  const int srow = wave * 16 + (lane >> 2);   // + i*64
  const int cg = (lane & 3) ^ ((srow >> 1) & 3);
  const int a0 = srow < rows ? srow : rows - 1;
  const int a1 = srow + 64 < rows ? srow + 64 : rows - 1;
  const unsigned short* gA0 = A + (size_t)(row0 + a0) * K + cg * 8;
  const unsigned short* gA1 = A + (size_t)(row0 + a1) * K + cg * 8;
  const unsigned short* gB0 = Wexp + (size_t)(bcol + srow) * K + cg * 8;
  const unsigned short* gB1 = Wexp + (size_t)(bcol + srow + 64) * K + cg * 8;

  f32x16 acc[2][2] = {};
  const int aRowB = wr * 64 + lr32;
  const int bRowB = wc * 64 + lr32;
  // Read-side swizzled chunk offsets (shorts) for k-half kh: chunk = 2*kh+l5,
  // XOR term = (row>>1)&3 reduces to (lr32>>1)&3 (other row parts %4==0 after >>1).
  const int rx = (lr32 >> 1) & 3;
  const int sw0 = ((0 * 2 + l5) ^ rx) * 8;
  const int sw1 = ((1 * 2 + l5) ^ rx) * 8;

  const int nk = K / BK;

  // prologue stage into buf 0
  {
    char* da = (char*)&sA[0][0] + wave * 1024;
    char* db = (char*)&sB[0][0] + wave * 1024;
    gload16(gA0, da);
    gload16(gA1, da + 4096);
    gload16(gB0, db);
    gload16(gB1, db + 4096);
  }
  __syncthreads();

  int buf = 0;
  for (int t = 0; t < nk; ++t) {
    if (t + 1 < nk) {
      const int k0 = (t + 1) * BK;
      char* da = (char*)&sA[buf ^ 1][0] + wave * 1024;
      char* db = (char*)&sB[buf ^ 1][0] + wave * 1024;
      gload16(gA0 + k0, da);
      gload16(gA1 + k0, da + 4096);
      gload16(gB0 + k0, db);
      gload16(gB1 + k0, db + 4096);
    }
    bf16x8 aF[2][2], bF[2][2];   // [frag][k-half]
#pragma unroll
    for (int m = 0; m < 2; ++m) {
      const unsigned short* rp = &sA[buf][(aRowB + m * 32) * BK];
      aF[m][0] = *reinterpret_cast<const bf16x8*>(rp + sw0);
      aF[m][1] = *reinterpret_cast<const bf16x8*>(rp + sw1);
    }
#pragma unroll
    for (int n = 0; n < 2; ++n) {
      const unsigned short* rp = &sB[buf][(bRowB + n * 32) * BK];
      bF[n][0] = *reinterpret_cast<const bf16x8*>(rp + sw0);
      bF[n][1] = *reinterpret_cast<const bf16x8*>(rp + sw1);
    }
#pragma unroll
    for (int kh = 0; kh < 2; ++kh)
#pragma unroll
      for (int m = 0; m < 2; ++m)
#pragma unroll
        for (int n = 0; n < 2; ++n)
          acc[m][n] = __builtin_amdgcn_mfma_f32_32x32x16_bf16(
              aF[m][kh], bF[n][kh], acc[m][n], 0, 0, 0);
    __syncthreads();
    buf ^= 1;
  }

  // Epilogue. C/D (m74/m101): col = lane&31, row = (r&3)+8*(r>>2)+4*(lane>>5).
  const float* __restrict__ be = bias + (size_t)e * N;
  const int colBase = bcol + wc * 64 + lr32;
  const int rowWave = wr * 64 + 4 * l5;
#pragma unroll
  for (int fn = 0; fn < 2; ++fn) {
    const int col = colBase + fn * 32;
    const float bv = be[col];
#pragma unroll
    for (int fm = 0; fm < 2; ++fm) {
      const int rBase = rowWave + fm * 32;
#pragma unroll
      for (int r = 0; r < 16; ++r) {
        const int rr = rBase + (r & 3) + 8 * (r >> 2);
        if (rr < rows) {
          float v = acc[fm][fn][r] + bv;
          if (GELU) v = fast_gelu(v);
          const size_t idx = (size_t)(row0 + rr) * N + col;
          if (OUTBF) ((unsigned short*)Cv)[idx] = f2bf(v);
          else       ((float*)Cv)[idx] = v;
        }
      }
    }
  }
}

extern "C" void kernel_launch(void* const* d_in, const int* in_sizes, int n_in,
                              void* d_out, int out_size, void* d_ws, size_t ws_size,
                              hipStream_t stream) {
  const float* inp = (const float*)d_in[0];
  const float* w1  = (const float*)d_in[1];
  const float* b1  = (const float*)d_in[2];
  const float* w2  = (const float*)d_in[3];
  const float* b2  = (const float*)d_in[4];
  const int*   cnt = (const int*)d_in[5];

  const int E = in_sizes[5];
  const int H = in_sizes[2] / E;       // b1 is [E,H]
  const int D = in_sizes[4] / E;       // b2 is [E,D]
  const int T = in_sizes[0] / D;       // inp is [T,D]

  char* ws = (char*)d_ws;
  int4* tbl = (int4*)ws;               // <= 72 entries
  int* ntp = (int*)(ws + 2048);
  size_t off = 4096;
  unsigned short* inp_bf = (unsigned short*)(ws + off); off += (size_t)T * D * 2;
  unsigned short* w1_bf  = (unsigned short*)(ws + off); off += (size_t)E * H * D * 2;
  unsigned short* w2_bf  = (unsigned short*)(ws + off); off += (size_t)E * D * H * 2;
  unsigned short* h_bf   = (unsigned short*)(ws + off); off += (size_t)T * H * 2;
  (void)ws_size; (void)n_in; (void)out_size;

  build_tiles<<<1, 64, 0, stream>>>(cnt, E, tbl, ntp);

  cvt_kernel<<<2048, 256, 0, stream>>>(inp, inp_bf, (long)T * D);
  cvt_kernel<<<2048, 256, 0, stream>>>(w1, w1_bf, (long)E * H * D);
  cvt_kernel<<<2048, 256, 0, stream>>>(w2, w2_bf, (long)E * D * H);

  const int maxTiles = T / BM + E;
  // GEMM1: [T,D] x [E,H,D] -> h [T,H], +b1, fast-gelu, bf16 out.
  dim3 g1(H / BN, maxTiles);
  grouped_gemm<1, 1><<<g1, 256, 0, stream>>>(inp_bf, w1_bf, b1, h_bf,
                                             tbl, ntp, H, D);
  // GEMM2: [T,H] x [E,D,H] -> out [T,D] f32, direct.
  dim3 g2(D / BN, maxTiles);
  grouped_gemm<0, 0><<<g2, 256, 0, stream>>>(h_bf, w2_bf, b2, d_out,
                                             tbl, ntp, D, H);
}